// Round 16
// baseline (411.967 us; speedup 1.0000x reference)
//
#include <hip/hip_runtime.h>
#include <hip/hip_bf16.h>

#define N_NODES 100000
#define N_EDGES 1600000
#define N_FEAT 7
#define HID 128
#define N_CLASS 5
#define N_GRAPHS 8
#define NPB 16  // nodes per block in fused layer kernels (grid 6250, 4 waves x 4 nodes)
#define TLP 136  // padded LDS row (bf16 elems): 272 B stride
#define TLP1 40  // layer-1 padded LDS row (K=32 zero-padded + 8)
#define NBKT 196       // ceil(N_NODES / 512) dst-buckets
#define BKT_SHIFT 9    // 512-node buckets
#define TILE 4096      // edges per partition block

typedef __hip_bfloat16 bf16;
typedef __attribute__((ext_vector_type(8))) short short8;   // 8 bf16 (4 VGPRs)
typedef __attribute__((ext_vector_type(4))) float f32x4;    // MFMA accumulator

// ---------------- CSR build v2 (r15-verified: part of the 480->382 win) ----------------

__global__ __launch_bounds__(256) void bucket_hist(const int* __restrict__ dst,
                                                   int* __restrict__ gcnt) {
    __shared__ int l[NBKT];
    int tid = threadIdx.x;
    for (int i = tid; i < NBKT; i += 256) l[i] = 0;
    __syncthreads();
    int e0 = blockIdx.x * TILE;
    int ne = N_EDGES - e0; if (ne > TILE) ne = TILE;
    for (int t = tid; t < ne; t += 256)
        atomicAdd(&l[dst[e0 + t] >> BKT_SHIFT], 1);
    __syncthreads();
    for (int i = tid; i < NBKT; i += 256)
        if (l[i]) atomicAdd(&gcnt[i], l[i]);
}

// 1 block: exclusive-scan bucket counts -> bstart/bcur; also zero pool+cnt,
// set rowptr[N].
__global__ __launch_bounds__(256) void scan_buckets(const int* __restrict__ gcnt,
                                                    int* __restrict__ bstart,
                                                    int* __restrict__ bcur,
                                                    int* __restrict__ rowptr,
                                                    float* __restrict__ pool) {
    __shared__ int s[256];
    int tid = threadIdx.x;
    int v = (tid < NBKT) ? gcnt[tid] : 0;
    s[tid] = v;
    __syncthreads();
    for (int o = 1; o < 256; o <<= 1) {
        int u = (tid >= o) ? s[tid - o] : 0;
        __syncthreads();
        s[tid] += u;
        __syncthreads();
    }
    if (tid < NBKT) { bstart[tid] = s[tid] - v; bcur[tid] = s[tid] - v; }
    if (tid == 0) rowptr[N_NODES] = N_EDGES;
    for (int i = tid; i < N_GRAPHS * HID + N_GRAPHS; i += 256) pool[i] = 0.f;
}

// Pass A: LDS counting-sort each edge tile by dst-bucket, write bucket-major.
__global__ __launch_bounds__(256) void partition_kernel(
        const int* __restrict__ src, const int* __restrict__ dst,
        const float* __restrict__ ea, int* __restrict__ bcur,
        int2* __restrict__ tmp2, int* __restrict__ tmpd) {
    __shared__ int lsrc[TILE], lea[TILE], ldst[TILE];   // 48 KB
    __shared__ int cnt[NBKT], gbase[NBKT];
    __shared__ int off[256];
    int tid = threadIdx.x;
    int e0 = blockIdx.x * TILE;
    int nedge = N_EDGES - e0; if (nedge > TILE) nedge = TILE;

    for (int bkt = tid; bkt < NBKT; bkt += 256) cnt[bkt] = 0;
    __syncthreads();
    for (int t = tid; t < nedge; t += 256)
        atomicAdd(&cnt[dst[e0 + t] >> BKT_SHIFT], 1);
    __syncthreads();
    off[tid] = (tid < NBKT) ? cnt[tid] : 0;
    __syncthreads();
    for (int o = 1; o < 256; o <<= 1) {                  // Hillis-Steele inclusive
        int u = (tid >= o) ? off[tid - o] : 0;
        __syncthreads();
        off[tid] += u;
        __syncthreads();
    }
    if (tid < NBKT) {
        off[tid] -= cnt[tid];                            // inclusive -> exclusive
        gbase[tid] = atomicAdd(&bcur[tid], cnt[tid]);    // reserve global bucket range
    }
    __syncthreads();
    if (tid < NBKT) cnt[tid] = 0;                        // reuse as rank counter
    __syncthreads();
    for (int t = tid; t < nedge; t += 256) {
        int d = dst[e0 + t];
        int bkt = d >> BKT_SHIFT;
        int sp = off[bkt] + atomicAdd(&cnt[bkt], 1);     // sorted slot in tile
        lsrc[sp] = src[e0 + t];
        lea[sp] = __float_as_int(ea[e0 + t]);
        ldst[sp] = d;
    }
    __syncthreads();
    for (int t = tid; t < nedge; t += 256) {             // bucket-grouped writeout
        int d = ldst[t];
        int bkt = d >> BKT_SHIFT;
        int gi = gbase[bkt] + (t - off[bkt]);
        tmp2[gi] = make_int2(lsrc[t], lea[t]);
        tmpd[gi] = d;
    }
}

// Pass B: one block per bucket. LDS per-node hist + scan -> rowptr segment;
// then scatter csr within the bucket's own ~100KB window.
__global__ __launch_bounds__(512) void bucket_sort(
        const int2* __restrict__ tmp2, const int* __restrict__ tmpd,
        const int* __restrict__ bstart, const int* __restrict__ gcnt,
        int* __restrict__ rowptr, int2* __restrict__ csr) {
    __shared__ int s[512];
    __shared__ int lcur[512];
    int tid = threadIdx.x;
    int b = blockIdx.x;
    int nb0 = b << BKT_SHIFT;
    int r0 = bstart[b];
    int r1 = r0 + gcnt[b];
    s[tid] = 0;
    __syncthreads();
    for (int i = r0 + tid; i < r1; i += 512)
        atomicAdd(&s[tmpd[i] - nb0], 1);
    __syncthreads();
    int v = s[tid];
    for (int o = 1; o < 512; o <<= 1) {                  // inclusive scan
        int u = (tid >= o) ? s[tid - o] : 0;
        __syncthreads();
        s[tid] += u;
        __syncthreads();
    }
    int excl = s[tid] - v;
    lcur[tid] = excl;
    int n = nb0 + tid;
    if (n < N_NODES) rowptr[n] = r0 + excl;
    __syncthreads();
    for (int i = r0 + tid; i < r1; i += 512) {
        int d = tmpd[i];
        int p = r0 + atomicAdd(&lcur[d - nb0], 1);
        csr[p] = tmp2[i];
    }
}

// ---------------- merged pre-pack: Wp2, Wp3, Wp1, xp in one launch ----------------
// B-frag for mfma_f32_16x16x32_bf16: lane l holds B[k=(l>>4)*8+q][col=l&15].

__device__ __forceinline__ void pack_w_body(const float* W, bf16* Wp, int t) {
    int l = t & 63;
    int kk = (t >> 6) & 3;
    int jt = t >> 8;
    int kbase = kk * 32 + (l >> 4) * 8;
    int j = jt * 16 + (l & 15);
#pragma unroll
    for (int q = 0; q < 8; ++q)
        Wp[t * 8 + q] = __float2bfloat16(W[(kbase + q) * HID + j]);
}

__global__ __launch_bounds__(256) void pack_all(
        const float* __restrict__ W2, const float* __restrict__ W3,
        const float* __restrict__ W1, const float* __restrict__ x,
        bf16* __restrict__ Wp2, bf16* __restrict__ Wp3,
        bf16* __restrict__ Wp1, bf16* __restrict__ xp) {
    int bid = blockIdx.x, tid = threadIdx.x;
    if (bid < 8) {
        pack_w_body(W2, Wp2, bid * 256 + tid);
    } else if (bid < 16) {
        pack_w_body(W3, Wp3, (bid - 8) * 256 + tid);
    } else if (bid < 18) {
        int t = (bid - 16) * 256 + tid;          // 0..511: K=7 zero-padded to 32
        if (t < 512) {
            int l = t & 63;
            int jt = t >> 6;
            int j = jt * 16 + (l & 15);
#pragma unroll
            for (int q = 0; q < 8; ++q) {
                int k = (l >> 4) * 8 + q;
                Wp1[t * 8 + q] = __float2bfloat16(k < N_FEAT ? W1[k * HID + j] : 0.f);
            }
        }
    } else {
        int n = (bid - 18) * 256 + tid;          // x: fp32 [N][7] -> bf16 [N][8]
        if (n < N_NODES) {
            unsigned short pk[8];
#pragma unroll
            for (int k = 0; k < N_FEAT; ++k) {
                bf16 h = __float2bfloat16(x[n * N_FEAT + k]);
                pk[k] = *(unsigned short*)&h;
            }
            pk[7] = 0;
            *(uint4*)&xp[(size_t)n * 8] = *(const uint4*)pk;
        }
    }
}

// ---------------- Fused layer 1: gather(xp, in=7) + MFMA ----------------
__global__ __launch_bounds__(256) void layer1_fused(
        const bf16* __restrict__ xp, const int2* __restrict__ csr,
        const int* __restrict__ rowptr, const float* __restrict__ We,
        const float* __restrict__ be, const bf16* __restrict__ Wp1,
        const float* __restrict__ b, bf16* __restrict__ hout) {
    __shared__ __align__(16) unsigned short tl[NPB][TLP1];   // 1.28 KB
    int tid = threadIdx.x;
    int wave = tid >> 6;
    int lane = tid & 63;
    int sub = lane >> 4;
    int l = lane & 15;
    int n0 = blockIdx.x * NPB;

    for (int i = tid; i < NPB * TLP1; i += 256) ((unsigned short*)tl)[i] = 0;

    float we[N_FEAT], bee[N_FEAT], p[N_FEAT];
#pragma unroll
    for (int k = 0; k < N_FEAT; ++k) { we[k] = We[k]; bee[k] = be[k]; p[k] = 0.f; }
    __syncthreads();   // zero-init visible before lane-0 t-writes

    const uint4* xp4 = (const uint4*)xp;
    int m = wave * 4 + sub;
    int n = n0 + m;
    int r0 = rowptr[n], r1 = rowptr[n + 1];
    for (int i = r0 + l; i < r1; i += 16) {
        int2 sa = csr[i];
        float a = __int_as_float(sa.y);
        uint4 rv = xp4[sa.x];                        // whole 7-feat row, one load
#pragma unroll
        for (int p_ = 0; p_ < 4; ++p_) {
            unsigned u = ((const unsigned*)&rv)[p_];
            float f0 = __uint_as_float(u << 16);
            float m0 = f0 + a * we[2 * p_] + bee[2 * p_];
            p[2 * p_] += m0 > 0.f ? m0 : 0.f;
            if (2 * p_ + 1 < N_FEAT) {
                float f1 = __uint_as_float(u & 0xffff0000u);
                float m1 = f1 + a * we[2 * p_ + 1] + bee[2 * p_ + 1];
                p[2 * p_ + 1] += m1 > 0.f ? m1 : 0.f;
            }
        }
    }
#pragma unroll
    for (int off = 8; off >= 1; off >>= 1)
#pragma unroll
        for (int k = 0; k < N_FEAT; ++k)
            p[k] += __shfl_xor(p[k], off, 16);
    if (l == 0) {
        uint4 sv = xp4[n];
#pragma unroll
        for (int k = 0; k < N_FEAT; ++k) {
            unsigned u = ((const unsigned*)&sv)[k >> 1];
            float fs = __uint_as_float((k & 1) ? (u & 0xffff0000u) : (u << 16));
            bf16 hb = __float2bfloat16(p[k] + fs);
            tl[m][k] = *(unsigned short*)&hb;
        }
    }
    __syncthreads();

    // MFMA node-update: one k-step (K=32, k>=7 are zeros)
    // Verified mapping (m89): A lane l: row=l&15, k=(l>>4)*8+q;
    //                         B lane l: col=l&15, k=(l>>4)*8+q;
    //                         D lane l: col=l&15, row=(l>>4)*4+reg.
    int c = lane & 15;
    int kq = lane >> 4;
    int jt0 = wave * 2, jt1 = jt0 + 1;
    f32x4 d0 = {0.f, 0.f, 0.f, 0.f}, d1 = {0.f, 0.f, 0.f, 0.f};
    const short8* wp = (const short8*)Wp1;
    short8 aF = *(const short8*)&tl[c][kq * 8];
    short8 b0 = wp[jt0 * 64 + lane];
    short8 b1 = wp[jt1 * 64 + lane];
    d0 = __builtin_amdgcn_mfma_f32_16x16x32_bf16(aF, b0, d0, 0, 0, 0);
    d1 = __builtin_amdgcn_mfma_f32_16x16x32_bf16(aF, b1, d1, 0, 0, 0);
    float bv0 = b[jt0 * 16 + c];
    float bv1 = b[jt1 * 16 + c];
#pragma unroll
    for (int i = 0; i < 4; ++i) {
        int mm = kq * 4 + i;
        size_t base = (size_t)(n0 + mm) * HID;
        float v0 = d0[i] + bv0;
        float v1 = d1[i] + bv1;
        hout[base + jt0 * 16 + c] = __float2bfloat16(v0 > 0.f ? v0 : 0.f);
        hout[base + jt1 * 16 + c] = __float2bfloat16(v1 > 0.f ? v1 : 0.f);
    }
}

// ---------------- Fused hidden layer + optional pooling epilogue ----------------
// POOL=0: write bf16 hout rows (feeds next gather). POOL=1 (layer 3): h3 is
// consumed ONLY by mean-pool, so skip the 25.6 MB hout write; accumulate
// relu(v) into LDS pool tile pl[8][128] (batch sorted -> block spans <=2
// graphs), flush ~128-256 global f32 atomics per block (~800K total over
// 1024 addresses -- well under L2 atomic throughput). Also removes the
// pool_kernel dispatch + its 25.6 MB read, and skips the h3 bf16 rounding
// (closer to the f32 reference).
// hout MUST differ from hin (POOL=0).
template<int POOL>
__global__ __launch_bounds__(256) void hidden_layer(
        const bf16* __restrict__ hin, const int2* __restrict__ csr,
        const int* __restrict__ rowptr, const float* __restrict__ We,
        const float* __restrict__ be, const bf16* __restrict__ Wp,
        const float* __restrict__ b, bf16* __restrict__ hout,
        const int* __restrict__ batch, float* __restrict__ gpool,
        float* __restrict__ gcnt) {
    __shared__ __align__(16) unsigned short tl[NPB][TLP];   // bf16 bits, 4.3 KB
    __shared__ float pl[N_GRAPHS][HID];                      // 4 KB (POOL only)
    __shared__ int bb[NPB];
    int tid = threadIdx.x;
    int wave = tid >> 6;
    int lane = tid & 63;
    int el = lane >> 4;          // edge slot 0..3
    int fc = lane & 15;          // feature chunk: feats fc*8 .. fc*8+7
    int n0 = blockIdx.x * NPB;

    if (POOL) {
        for (int i = tid; i < N_GRAPHS * HID; i += 256) ((float*)pl)[i] = 0.f;
        if (tid < NPB) bb[tid] = batch[n0 + tid];
    }

    float we8[8], be8[8];
#pragma unroll
    for (int q = 0; q < 8; ++q) {
        we8[q] = We[fc * 8 + q];
        be8[q] = be[fc * 8 + q];
    }

    const uint4* hin4 = (const uint4*)hin;   // one 128-feat bf16 row = 16 uint4

    for (int loc = 0; loc < 4; ++loc) {
        int m = wave * 4 + loc;
        int n = n0 + m;
        int r0 = rowptr[n], r1 = rowptr[n + 1];
        float acc[8];
#pragma unroll
        for (int q = 0; q < 8; ++q) acc[q] = 0.f;
#pragma unroll 2
        for (int i = r0 + el; i < r1; i += 4) {
            int2 sa = csr[i];
            int s = sa.x;
            float a = __int_as_float(sa.y);
            uint4 rv = hin4[(size_t)s * 16 + fc];
#pragma unroll
            for (int p = 0; p < 4; ++p) {
                unsigned u = ((const unsigned*)&rv)[p];
                float f0 = __uint_as_float(u << 16);          // low bf16
                float f1 = __uint_as_float(u & 0xffff0000u);  // high bf16
                float m0 = f0 + a * we8[2 * p] + be8[2 * p];
                float m1 = f1 + a * we8[2 * p + 1] + be8[2 * p + 1];
                acc[2 * p]     += m0 > 0.f ? m0 : 0.f;
                acc[2 * p + 1] += m1 > 0.f ? m1 : 0.f;
            }
        }
        // combine the 4 edge slots (lanes l, l^16, l^32 share fc)
#pragma unroll
        for (int q = 0; q < 8; ++q) {
            acc[q] += __shfl_xor(acc[q], 16, 64);
            acc[q] += __shfl_xor(acc[q], 32, 64);
        }
        if (el == 0) {
            uint4 sv = hin4[(size_t)n * 16 + fc];
            unsigned short pk[8];
#pragma unroll
            for (int p = 0; p < 4; ++p) {
                unsigned u = ((const unsigned*)&sv)[p];
                float v0 = acc[2 * p]     + __uint_as_float(u << 16);
                float v1 = acc[2 * p + 1] + __uint_as_float(u & 0xffff0000u);
                bf16 h0 = __float2bfloat16(v0);
                bf16 h1 = __float2bfloat16(v1);
                pk[2 * p]     = *(unsigned short*)&h0;
                pk[2 * p + 1] = *(unsigned short*)&h1;
            }
            *(uint4*)&tl[m][fc * 8] = *(const uint4*)pk;   // one ds_write_b128
        }
    }
    __syncthreads();   // orders pl zero-init + bb load + tl writes

    // MFMA node-update: out[m][j] = relu(b[j] + sum_k t[m][k] * W[k][j])
    // Verified mapping (m89): A lane l: row=l&15, k=(l>>4)*8+q;
    //                         B lane l: col=l&15, k=(l>>4)*8+q;
    //                         D lane l: col=l&15, row=(l>>4)*4+reg.
    int c = lane & 15;           // A row / D col
    int kq = lane >> 4;          // k-chunk selector
    int jt0 = wave * 2, jt1 = jt0 + 1;
    f32x4 d0 = {0.f, 0.f, 0.f, 0.f}, d1 = {0.f, 0.f, 0.f, 0.f};
    const short8* wp = (const short8*)Wp;
#pragma unroll
    for (int kk = 0; kk < 4; ++kk) {
        short8 a  = *(const short8*)&tl[c][kk * 32 + kq * 8];
        short8 b0 = wp[(jt0 * 4 + kk) * 64 + lane];
        short8 b1 = wp[(jt1 * 4 + kk) * 64 + lane];
        d0 = __builtin_amdgcn_mfma_f32_16x16x32_bf16(a, b0, d0, 0, 0, 0);
        d1 = __builtin_amdgcn_mfma_f32_16x16x32_bf16(a, b1, d1, 0, 0, 0);
    }
    float bv0 = b[jt0 * 16 + c];
    float bv1 = b[jt1 * 16 + c];
#pragma unroll
    for (int i = 0; i < 4; ++i) {
        int m = kq * 4 + i;
        float v0 = d0[i] + bv0;
        float v1 = d1[i] + bv1;
        v0 = v0 > 0.f ? v0 : 0.f;
        v1 = v1 > 0.f ? v1 : 0.f;
        if (POOL) {
            int g = bb[m];
            atomicAdd(&pl[g][jt0 * 16 + c], v0);
            atomicAdd(&pl[g][jt1 * 16 + c], v1);
        } else {
            size_t base = (size_t)(n0 + m) * HID;
            hout[base + jt0 * 16 + c] = __float2bfloat16(v0);
            hout[base + jt1 * 16 + c] = __float2bfloat16(v1);
        }
    }

    if (POOL) {
        __syncthreads();
        int gmin = bb[0], gmax = bb[NPB - 1];       // batch sorted
        int j = tid & 127;
        for (int g = gmin + (tid >> 7); g <= gmax; g += 2) {
            float v = pl[g][j];
            if (v != 0.f) atomicAdd(&gpool[g * HID + j], v);
        }
        if (tid == 0) {
            int cg = bb[0], cc = 0;
#pragma unroll
            for (int i = 0; i < NPB; ++i) {
                int g = bb[i];
                if (g != cg) { atomicAdd(&gcnt[cg], (float)cc); cg = g; cc = 0; }
                cc++;
            }
            atomicAdd(&gcnt[cg], (float)cc);
        }
    }
}

// ---------------- Head ----------------

__global__ void final_kernel(const float* __restrict__ pool, const float* __restrict__ cnt,
                             const float* __restrict__ Wlin, const float* __restrict__ blin,
                             float* __restrict__ out) {
    int idx = threadIdx.x;
    if (idx >= N_GRAPHS * N_CLASS) return;
    int g = idx / N_CLASS, c = idx % N_CLASS;
    float invc = 1.f / fmaxf(cnt[g], 1.f);
    float acc = blin[c];
    for (int j = 0; j < HID; ++j) acc += pool[g * HID + j] * invc * Wlin[j * N_CLASS + c];
    out[idx] = acc;
}

extern "C" void kernel_launch(void* const* d_in, const int* in_sizes, int n_in,
                              void* d_out, int out_size, void* d_ws, size_t ws_size,
                              hipStream_t stream) {
    const float* x    = (const float*)d_in[0];
    const int*   ei   = (const int*)d_in[1];
    const float* ea   = (const float*)d_in[2];
    const int*   batch= (const int*)d_in[3];
    const float* We1  = (const float*)d_in[4];
    const float* be1  = (const float*)d_in[5];
    const float* W1   = (const float*)d_in[6];
    const float* b1   = (const float*)d_in[7];
    const float* We2  = (const float*)d_in[8];
    const float* be2  = (const float*)d_in[9];
    const float* W2   = (const float*)d_in[10];
    const float* b2   = (const float*)d_in[11];
    const float* We3  = (const float*)d_in[12];
    const float* be3  = (const float*)d_in[13];
    const float* W3   = (const float*)d_in[14];
    const float* b3   = (const float*)d_in[15];
    const float* Wlin = (const float*)d_in[16];
    const float* blin = (const float*)d_in[17];

    const int* src = ei;
    const int* dst = ei + N_EDGES;

    // workspace layout (csr first: 16B-aligned at base)
    char* w = (char*)d_ws;
    int2*  csr    = (int2*)w;                    w += sizeof(int2) * (size_t)N_EDGES;   // 12.8 MB
    bf16*  Wp2    = (bf16*)w;                    w += sizeof(bf16) * 8 * 4 * 64 * 8;    // 32 KB
    bf16*  Wp3    = (bf16*)w;                    w += sizeof(bf16) * 8 * 4 * 64 * 8;    // 32 KB
    bf16*  Wp1    = (bf16*)w;                    w += sizeof(bf16) * 8 * 64 * 8;        // 8 KB
    bf16*  xp     = (bf16*)w;                    w += sizeof(bf16) * (size_t)N_NODES * 8; // 1.6 MB
    bf16*  A      = (bf16*)w;                    w += sizeof(bf16) * (size_t)N_NODES * HID; // 25.6 MB
    bf16*  B      = (bf16*)w;                    w += sizeof(bf16) * (size_t)N_NODES * HID; // 25.6 MB
    float* pool   = (float*)w;                   w += sizeof(float) * N_GRAPHS * HID;
    float* cnt    = (float*)w;                   w += sizeof(float) * N_GRAPHS;
    int*   rowptr = (int*)w;                     w += sizeof(int) * (N_NODES + 1);
    int*   gcnt   = (int*)w;                     w += sizeof(int) * NBKT;
    int*   bstart = (int*)w;                     w += sizeof(int) * NBKT;
    int*   bcur   = (int*)w;                     w += sizeof(int) * NBKT;

    // partition temporaries alias A (25.6 MB >= 12.8 + 6.4); A is first written
    // by layer1_fused, strictly after bucket_sort on the same stream.
    int2* tmp2 = (int2*)A;
    int*  tmpd = (int*)((char*)A + sizeof(int2) * (size_t)N_EDGES);

    // ---- CSR build v2 + packs (10 dispatches total) ----
    hipMemsetAsync(gcnt, 0, sizeof(int) * NBKT, stream);
    bucket_hist<<<(N_EDGES + TILE - 1) / TILE, 256, 0, stream>>>(dst, gcnt);
    pack_all<<<18 + (N_NODES + 255) / 256, 256, 0, stream>>>(W2, W3, W1, x, Wp2, Wp3, Wp1, xp);
    scan_buckets<<<1, 256, 0, stream>>>(gcnt, bstart, bcur, rowptr, pool);
    partition_kernel<<<(N_EDGES + TILE - 1) / TILE, 256, 0, stream>>>(src, dst, ea, bcur, tmp2, tmpd);
    bucket_sort<<<NBKT, 512, 0, stream>>>(tmp2, tmpd, bstart, gcnt, rowptr, csr);

    // ---- Layer 1 (fused gather + MFMA, packed x) ----
    layer1_fused<<<N_NODES / NPB, 256, 0, stream>>>(xp, csr, rowptr, We1, be1, Wp1, b1, A);

    // ---- Layer 2: A -> B ----
    hidden_layer<0><<<N_NODES / NPB, 256, 0, stream>>>(A, csr, rowptr, We2, be2, Wp2, b2, B,
                                                       batch, nullptr, nullptr);

    // ---- Layer 3: B -> pool (fused mean-pool accumulation, no h3 write) ----
    hidden_layer<1><<<N_NODES / NPB, 256, 0, stream>>>(B, csr, rowptr, We3, be3, Wp3, b3, nullptr,
                                                       batch, pool, cnt);

    // ---- Head ----
    final_kernel<<<1, 64, 0, stream>>>(pool, cnt, Wlin, blin, (float*)d_out);
}

// Round 17
// 384.398 us; speedup vs baseline: 1.0717x; 1.0717x over previous
//
#include <hip/hip_runtime.h>
#include <hip/hip_bf16.h>

#define N_NODES 100000
#define N_EDGES 1600000
#define N_FEAT 7
#define HID 128
#define N_CLASS 5
#define N_GRAPHS 8
#define NPB 16  // nodes per block in fused layer kernels (grid 6250, 4 waves x 4 nodes)
#define TLP 136  // padded LDS row (bf16 elems): 272 B stride
#define TLP1 40  // layer-1 padded LDS row (K=32 zero-padded + 8)
#define NBKT 196       // ceil(N_NODES / 512) dst-buckets
#define BKT_SHIFT 9    // 512-node buckets
#define TILE 4096      // edges per partition block

typedef __hip_bfloat16 bf16;
typedef __attribute__((ext_vector_type(8))) short short8;   // 8 bf16 (4 VGPRs)
typedef __attribute__((ext_vector_type(4))) float f32x4;    // MFMA accumulator

// ---------------- CSR build v2 (r15-verified: part of the 480->382 win) ----------------

__global__ __launch_bounds__(256) void bucket_hist(const int* __restrict__ dst,
                                                   int* __restrict__ gcnt) {
    __shared__ int l[NBKT];
    int tid = threadIdx.x;
    for (int i = tid; i < NBKT; i += 256) l[i] = 0;
    __syncthreads();
    int e0 = blockIdx.x * TILE;
    int ne = N_EDGES - e0; if (ne > TILE) ne = TILE;
    for (int t = tid; t < ne; t += 256)
        atomicAdd(&l[dst[e0 + t] >> BKT_SHIFT], 1);
    __syncthreads();
    for (int i = tid; i < NBKT; i += 256)
        if (l[i]) atomicAdd(&gcnt[i], l[i]);
}

// 1 block: exclusive-scan bucket counts -> bstart/bcur; also zero pool+cnt,
// set rowptr[N].
__global__ __launch_bounds__(256) void scan_buckets(const int* __restrict__ gcnt,
                                                    int* __restrict__ bstart,
                                                    int* __restrict__ bcur,
                                                    int* __restrict__ rowptr,
                                                    float* __restrict__ pool) {
    __shared__ int s[256];
    int tid = threadIdx.x;
    int v = (tid < NBKT) ? gcnt[tid] : 0;
    s[tid] = v;
    __syncthreads();
    for (int o = 1; o < 256; o <<= 1) {
        int u = (tid >= o) ? s[tid - o] : 0;
        __syncthreads();
        s[tid] += u;
        __syncthreads();
    }
    if (tid < NBKT) { bstart[tid] = s[tid] - v; bcur[tid] = s[tid] - v; }
    if (tid == 0) rowptr[N_NODES] = N_EDGES;
    for (int i = tid; i < N_GRAPHS * HID + N_GRAPHS; i += 256) pool[i] = 0.f;
}

// Pass A: LDS counting-sort each edge tile by dst-bucket, write bucket-major.
__global__ __launch_bounds__(256) void partition_kernel(
        const int* __restrict__ src, const int* __restrict__ dst,
        const float* __restrict__ ea, int* __restrict__ bcur,
        int2* __restrict__ tmp2, int* __restrict__ tmpd) {
    __shared__ int lsrc[TILE], lea[TILE], ldst[TILE];   // 48 KB
    __shared__ int cnt[NBKT], gbase[NBKT];
    __shared__ int off[256];
    int tid = threadIdx.x;
    int e0 = blockIdx.x * TILE;
    int nedge = N_EDGES - e0; if (nedge > TILE) nedge = TILE;

    for (int bkt = tid; bkt < NBKT; bkt += 256) cnt[bkt] = 0;
    __syncthreads();
    for (int t = tid; t < nedge; t += 256)
        atomicAdd(&cnt[dst[e0 + t] >> BKT_SHIFT], 1);
    __syncthreads();
    off[tid] = (tid < NBKT) ? cnt[tid] : 0;
    __syncthreads();
    for (int o = 1; o < 256; o <<= 1) {                  // Hillis-Steele inclusive
        int u = (tid >= o) ? off[tid - o] : 0;
        __syncthreads();
        off[tid] += u;
        __syncthreads();
    }
    if (tid < NBKT) {
        off[tid] -= cnt[tid];                            // inclusive -> exclusive
        gbase[tid] = atomicAdd(&bcur[tid], cnt[tid]);    // reserve global bucket range
    }
    __syncthreads();
    if (tid < NBKT) cnt[tid] = 0;                        // reuse as rank counter
    __syncthreads();
    for (int t = tid; t < nedge; t += 256) {
        int d = dst[e0 + t];
        int bkt = d >> BKT_SHIFT;
        int sp = off[bkt] + atomicAdd(&cnt[bkt], 1);     // sorted slot in tile
        lsrc[sp] = src[e0 + t];
        lea[sp] = __float_as_int(ea[e0 + t]);
        ldst[sp] = d;
    }
    __syncthreads();
    for (int t = tid; t < nedge; t += 256) {             // bucket-grouped writeout
        int d = ldst[t];
        int bkt = d >> BKT_SHIFT;
        int gi = gbase[bkt] + (t - off[bkt]);
        tmp2[gi] = make_int2(lsrc[t], lea[t]);
        tmpd[gi] = d;
    }
}

// Pass B: one block per bucket. LDS per-node hist + scan -> rowptr segment;
// then scatter csr within the bucket's own ~100KB window.
__global__ __launch_bounds__(512) void bucket_sort(
        const int2* __restrict__ tmp2, const int* __restrict__ tmpd,
        const int* __restrict__ bstart, const int* __restrict__ gcnt,
        int* __restrict__ rowptr, int2* __restrict__ csr) {
    __shared__ int s[512];
    __shared__ int lcur[512];
    int tid = threadIdx.x;
    int b = blockIdx.x;
    int nb0 = b << BKT_SHIFT;
    int r0 = bstart[b];
    int r1 = r0 + gcnt[b];
    s[tid] = 0;
    __syncthreads();
    for (int i = r0 + tid; i < r1; i += 512)
        atomicAdd(&s[tmpd[i] - nb0], 1);
    __syncthreads();
    int v = s[tid];
    for (int o = 1; o < 512; o <<= 1) {                  // inclusive scan
        int u = (tid >= o) ? s[tid - o] : 0;
        __syncthreads();
        s[tid] += u;
        __syncthreads();
    }
    int excl = s[tid] - v;
    lcur[tid] = excl;
    int n = nb0 + tid;
    if (n < N_NODES) rowptr[n] = r0 + excl;
    __syncthreads();
    for (int i = r0 + tid; i < r1; i += 512) {
        int d = tmpd[i];
        int p = r0 + atomicAdd(&lcur[d - nb0], 1);
        csr[p] = tmp2[i];
    }
}

// ---------------- merged pre-pack: Wp2, Wp3, Wp1, xp in one launch ----------------
// B-frag for mfma_f32_16x16x32_bf16: lane l holds B[k=(l>>4)*8+q][col=l&15].

__device__ __forceinline__ void pack_w_body(const float* W, bf16* Wp, int t) {
    int l = t & 63;
    int kk = (t >> 6) & 3;
    int jt = t >> 8;
    int kbase = kk * 32 + (l >> 4) * 8;
    int j = jt * 16 + (l & 15);
#pragma unroll
    for (int q = 0; q < 8; ++q)
        Wp[t * 8 + q] = __float2bfloat16(W[(kbase + q) * HID + j]);
}

__global__ __launch_bounds__(256) void pack_all(
        const float* __restrict__ W2, const float* __restrict__ W3,
        const float* __restrict__ W1, const float* __restrict__ x,
        bf16* __restrict__ Wp2, bf16* __restrict__ Wp3,
        bf16* __restrict__ Wp1, bf16* __restrict__ xp) {
    int bid = blockIdx.x, tid = threadIdx.x;
    if (bid < 8) {
        pack_w_body(W2, Wp2, bid * 256 + tid);
    } else if (bid < 16) {
        pack_w_body(W3, Wp3, (bid - 8) * 256 + tid);
    } else if (bid < 18) {
        int t = (bid - 16) * 256 + tid;          // 0..511: K=7 zero-padded to 32
        if (t < 512) {
            int l = t & 63;
            int jt = t >> 6;
            int j = jt * 16 + (l & 15);
#pragma unroll
            for (int q = 0; q < 8; ++q) {
                int k = (l >> 4) * 8 + q;
                Wp1[t * 8 + q] = __float2bfloat16(k < N_FEAT ? W1[k * HID + j] : 0.f);
            }
        }
    } else {
        int n = (bid - 18) * 256 + tid;          // x: fp32 [N][7] -> bf16 [N][8]
        if (n < N_NODES) {
            unsigned short pk[8];
#pragma unroll
            for (int k = 0; k < N_FEAT; ++k) {
                bf16 h = __float2bfloat16(x[n * N_FEAT + k]);
                pk[k] = *(unsigned short*)&h;
            }
            pk[7] = 0;
            *(uint4*)&xp[(size_t)n * 8] = *(const uint4*)pk;
        }
    }
}

// ---------------- Fused layer 1: gather(xp, in=7) + MFMA ----------------
__global__ __launch_bounds__(256) void layer1_fused(
        const bf16* __restrict__ xp, const int2* __restrict__ csr,
        const int* __restrict__ rowptr, const float* __restrict__ We,
        const float* __restrict__ be, const bf16* __restrict__ Wp1,
        const float* __restrict__ b, bf16* __restrict__ hout) {
    __shared__ __align__(16) unsigned short tl[NPB][TLP1];   // 1.28 KB
    int tid = threadIdx.x;
    int wave = tid >> 6;
    int lane = tid & 63;
    int sub = lane >> 4;
    int l = lane & 15;
    int n0 = blockIdx.x * NPB;

    for (int i = tid; i < NPB * TLP1; i += 256) ((unsigned short*)tl)[i] = 0;

    float we[N_FEAT], bee[N_FEAT], p[N_FEAT];
#pragma unroll
    for (int k = 0; k < N_FEAT; ++k) { we[k] = We[k]; bee[k] = be[k]; p[k] = 0.f; }
    __syncthreads();   // zero-init visible before lane-0 t-writes

    const uint4* xp4 = (const uint4*)xp;
    int m = wave * 4 + sub;
    int n = n0 + m;
    int r0 = rowptr[n], r1 = rowptr[n + 1];
    for (int i = r0 + l; i < r1; i += 16) {
        int2 sa = csr[i];
        float a = __int_as_float(sa.y);
        uint4 rv = xp4[sa.x];                        // whole 7-feat row, one load
#pragma unroll
        for (int p_ = 0; p_ < 4; ++p_) {
            unsigned u = ((const unsigned*)&rv)[p_];
            float f0 = __uint_as_float(u << 16);
            float m0 = f0 + a * we[2 * p_] + bee[2 * p_];
            p[2 * p_] += m0 > 0.f ? m0 : 0.f;
            if (2 * p_ + 1 < N_FEAT) {
                float f1 = __uint_as_float(u & 0xffff0000u);
                float m1 = f1 + a * we[2 * p_ + 1] + bee[2 * p_ + 1];
                p[2 * p_ + 1] += m1 > 0.f ? m1 : 0.f;
            }
        }
    }
#pragma unroll
    for (int off = 8; off >= 1; off >>= 1)
#pragma unroll
        for (int k = 0; k < N_FEAT; ++k)
            p[k] += __shfl_xor(p[k], off, 16);
    if (l == 0) {
        uint4 sv = xp4[n];
#pragma unroll
        for (int k = 0; k < N_FEAT; ++k) {
            unsigned u = ((const unsigned*)&sv)[k >> 1];
            float fs = __uint_as_float((k & 1) ? (u & 0xffff0000u) : (u << 16));
            bf16 hb = __float2bfloat16(p[k] + fs);
            tl[m][k] = *(unsigned short*)&hb;
        }
    }
    __syncthreads();

    // MFMA node-update: one k-step (K=32, k>=7 are zeros)
    // Verified mapping (m89): A lane l: row=l&15, k=(l>>4)*8+q;
    //                         B lane l: col=l&15, k=(l>>4)*8+q;
    //                         D lane l: col=l&15, row=(l>>4)*4+reg.
    int c = lane & 15;
    int kq = lane >> 4;
    int jt0 = wave * 2, jt1 = jt0 + 1;
    f32x4 d0 = {0.f, 0.f, 0.f, 0.f}, d1 = {0.f, 0.f, 0.f, 0.f};
    const short8* wp = (const short8*)Wp1;
    short8 aF = *(const short8*)&tl[c][kq * 8];
    short8 b0 = wp[jt0 * 64 + lane];
    short8 b1 = wp[jt1 * 64 + lane];
    d0 = __builtin_amdgcn_mfma_f32_16x16x32_bf16(aF, b0, d0, 0, 0, 0);
    d1 = __builtin_amdgcn_mfma_f32_16x16x32_bf16(aF, b1, d1, 0, 0, 0);
    float bv0 = b[jt0 * 16 + c];
    float bv1 = b[jt1 * 16 + c];
#pragma unroll
    for (int i = 0; i < 4; ++i) {
        int mm = kq * 4 + i;
        size_t base = (size_t)(n0 + mm) * HID;
        float v0 = d0[i] + bv0;
        float v1 = d1[i] + bv1;
        hout[base + jt0 * 16 + c] = __float2bfloat16(v0 > 0.f ? v0 : 0.f);
        hout[base + jt1 * 16 + c] = __float2bfloat16(v1 > 0.f ? v1 : 0.f);
    }
}

// ---------------- Fused hidden layer + optional pooling epilogue ----------------
// POOL=0: write bf16 hout rows. POOL=1 (layer 3): skip the 25.6 MB hout write;
// accumulate relu(v) into REGISTERS (r16 LDS-atomic version serialized the DS
// pipe 16-way: 143us, VALU-cycles unchanged -> pure stall). j-tiles are
// wave-disjoint, so for fixed j only the 4 kq-lanes {c,c+16,c+32,c+48}
// contribute: 2x2 reg accum (graph in {gmin,gmax} x j in {jt0,jt1}),
// 2 shfl_xor reduce over kq, then <=4 global atomics from lanes 0-15
// (~800K atomics over 1024 addrs -- proven cheap by old pool_kernel).
// Block spans <=2 graphs (batch sorted, ~12.5k nodes/graph).
// hout MUST differ from hin (POOL=0).
template<int POOL>
__global__ __launch_bounds__(256) void hidden_layer(
        const bf16* __restrict__ hin, const int2* __restrict__ csr,
        const int* __restrict__ rowptr, const float* __restrict__ We,
        const float* __restrict__ be, const bf16* __restrict__ Wp,
        const float* __restrict__ b, bf16* __restrict__ hout,
        const int* __restrict__ batch, float* __restrict__ gpool,
        float* __restrict__ gcnt) {
    __shared__ __align__(16) unsigned short tl[NPB][TLP];   // bf16 bits, 4.3 KB
    __shared__ int bb[NPB];                                  // 64 B (POOL only)
    int tid = threadIdx.x;
    int wave = tid >> 6;
    int lane = tid & 63;
    int el = lane >> 4;          // edge slot 0..3
    int fc = lane & 15;          // feature chunk: feats fc*8 .. fc*8+7
    int n0 = blockIdx.x * NPB;

    if (POOL && tid < NPB) bb[tid] = batch[n0 + tid];

    float we8[8], be8[8];
#pragma unroll
    for (int q = 0; q < 8; ++q) {
        we8[q] = We[fc * 8 + q];
        be8[q] = be[fc * 8 + q];
    }

    const uint4* hin4 = (const uint4*)hin;   // one 128-feat bf16 row = 16 uint4

    for (int loc = 0; loc < 4; ++loc) {
        int m = wave * 4 + loc;
        int n = n0 + m;
        int r0 = rowptr[n], r1 = rowptr[n + 1];
        float acc[8];
#pragma unroll
        for (int q = 0; q < 8; ++q) acc[q] = 0.f;
#pragma unroll 2
        for (int i = r0 + el; i < r1; i += 4) {
            int2 sa = csr[i];
            int s = sa.x;
            float a = __int_as_float(sa.y);
            uint4 rv = hin4[(size_t)s * 16 + fc];
#pragma unroll
            for (int p = 0; p < 4; ++p) {
                unsigned u = ((const unsigned*)&rv)[p];
                float f0 = __uint_as_float(u << 16);          // low bf16
                float f1 = __uint_as_float(u & 0xffff0000u);  // high bf16
                float m0 = f0 + a * we8[2 * p] + be8[2 * p];
                float m1 = f1 + a * we8[2 * p + 1] + be8[2 * p + 1];
                acc[2 * p]     += m0 > 0.f ? m0 : 0.f;
                acc[2 * p + 1] += m1 > 0.f ? m1 : 0.f;
            }
        }
        // combine the 4 edge slots (lanes l, l^16, l^32 share fc)
#pragma unroll
        for (int q = 0; q < 8; ++q) {
            acc[q] += __shfl_xor(acc[q], 16, 64);
            acc[q] += __shfl_xor(acc[q], 32, 64);
        }
        if (el == 0) {
            uint4 sv = hin4[(size_t)n * 16 + fc];
            unsigned short pk[8];
#pragma unroll
            for (int p = 0; p < 4; ++p) {
                unsigned u = ((const unsigned*)&sv)[p];
                float v0 = acc[2 * p]     + __uint_as_float(u << 16);
                float v1 = acc[2 * p + 1] + __uint_as_float(u & 0xffff0000u);
                bf16 h0 = __float2bfloat16(v0);
                bf16 h1 = __float2bfloat16(v1);
                pk[2 * p]     = *(unsigned short*)&h0;
                pk[2 * p + 1] = *(unsigned short*)&h1;
            }
            *(uint4*)&tl[m][fc * 8] = *(const uint4*)pk;   // one ds_write_b128
        }
    }
    __syncthreads();   // orders bb load + tl writes

    // MFMA node-update: out[m][j] = relu(b[j] + sum_k t[m][k] * W[k][j])
    // Verified mapping (m89): A lane l: row=l&15, k=(l>>4)*8+q;
    //                         B lane l: col=l&15, k=(l>>4)*8+q;
    //                         D lane l: col=l&15, row=(l>>4)*4+reg.
    int c = lane & 15;           // A row / D col
    int kq = lane >> 4;          // k-chunk selector
    int jt0 = wave * 2, jt1 = jt0 + 1;
    f32x4 d0 = {0.f, 0.f, 0.f, 0.f}, d1 = {0.f, 0.f, 0.f, 0.f};
    const short8* wp = (const short8*)Wp;
#pragma unroll
    for (int kk = 0; kk < 4; ++kk) {
        short8 a  = *(const short8*)&tl[c][kk * 32 + kq * 8];
        short8 b0 = wp[(jt0 * 4 + kk) * 64 + lane];
        short8 b1 = wp[(jt1 * 4 + kk) * 64 + lane];
        d0 = __builtin_amdgcn_mfma_f32_16x16x32_bf16(a, b0, d0, 0, 0, 0);
        d1 = __builtin_amdgcn_mfma_f32_16x16x32_bf16(a, b1, d1, 0, 0, 0);
    }
    float bv0 = b[jt0 * 16 + c];
    float bv1 = b[jt1 * 16 + c];

    if (POOL) {
        int gmin = bb[0], gmax = bb[NPB - 1];       // batch sorted
        float pg[2][2] = {{0.f, 0.f}, {0.f, 0.f}};  // [graph slot][j slot]
#pragma unroll
        for (int i = 0; i < 4; ++i) {
            int m = kq * 4 + i;
            float v0 = d0[i] + bv0;
            float v1 = d1[i] + bv1;
            v0 = v0 > 0.f ? v0 : 0.f;
            v1 = v1 > 0.f ? v1 : 0.f;
            if (bb[m] == gmin) { pg[0][0] += v0; pg[0][1] += v1; }
            else               { pg[1][0] += v0; pg[1][1] += v1; }
        }
        // reduce over kq: lanes {c, c+16, c+32, c+48}
#pragma unroll
        for (int s = 0; s < 2; ++s)
#pragma unroll
            for (int t = 0; t < 2; ++t) {
                pg[s][t] += __shfl_xor(pg[s][t], 16, 64);
                pg[s][t] += __shfl_xor(pg[s][t], 32, 64);
            }
        if (lane < 16) {
            atomicAdd(&gpool[gmin * HID + jt0 * 16 + c], pg[0][0]);
            atomicAdd(&gpool[gmin * HID + jt1 * 16 + c], pg[0][1]);
            if (gmax != gmin) {
                atomicAdd(&gpool[gmax * HID + jt0 * 16 + c], pg[1][0]);
                atomicAdd(&gpool[gmax * HID + jt1 * 16 + c], pg[1][1]);
            }
        }
        if (tid == 0) {
            int cg = bb[0], cc = 0;
#pragma unroll
            for (int i = 0; i < NPB; ++i) {
                int g = bb[i];
                if (g != cg) { atomicAdd(&gcnt[cg], (float)cc); cg = g; cc = 0; }
                cc++;
            }
            atomicAdd(&gcnt[cg], (float)cc);
        }
    } else {
#pragma unroll
        for (int i = 0; i < 4; ++i) {
            int m = kq * 4 + i;
            size_t base = (size_t)(n0 + m) * HID;
            float v0 = d0[i] + bv0;
            float v1 = d1[i] + bv1;
            hout[base + jt0 * 16 + c] = __float2bfloat16(v0 > 0.f ? v0 : 0.f);
            hout[base + jt1 * 16 + c] = __float2bfloat16(v1 > 0.f ? v1 : 0.f);
        }
    }
}

// ---------------- Head ----------------

__global__ void final_kernel(const float* __restrict__ pool, const float* __restrict__ cnt,
                             const float* __restrict__ Wlin, const float* __restrict__ blin,
                             float* __restrict__ out) {
    int idx = threadIdx.x;
    if (idx >= N_GRAPHS * N_CLASS) return;
    int g = idx / N_CLASS, c = idx % N_CLASS;
    float invc = 1.f / fmaxf(cnt[g], 1.f);
    float acc = blin[c];
    for (int j = 0; j < HID; ++j) acc += pool[g * HID + j] * invc * Wlin[j * N_CLASS + c];
    out[idx] = acc;
}

extern "C" void kernel_launch(void* const* d_in, const int* in_sizes, int n_in,
                              void* d_out, int out_size, void* d_ws, size_t ws_size,
                              hipStream_t stream) {
    const float* x    = (const float*)d_in[0];
    const int*   ei   = (const int*)d_in[1];
    const float* ea   = (const float*)d_in[2];
    const int*   batch= (const int*)d_in[3];
    const float* We1  = (const float*)d_in[4];
    const float* be1  = (const float*)d_in[5];
    const float* W1   = (const float*)d_in[6];
    const float* b1   = (const float*)d_in[7];
    const float* We2  = (const float*)d_in[8];
    const float* be2  = (const float*)d_in[9];
    const float* W2   = (const float*)d_in[10];
    const float* b2   = (const float*)d_in[11];
    const float* We3  = (const float*)d_in[12];
    const float* be3  = (const float*)d_in[13];
    const float* W3   = (const float*)d_in[14];
    const float* b3   = (const float*)d_in[15];
    const float* Wlin = (const float*)d_in[16];
    const float* blin = (const float*)d_in[17];

    const int* src = ei;
    const int* dst = ei + N_EDGES;

    // workspace layout (csr first: 16B-aligned at base)
    char* w = (char*)d_ws;
    int2*  csr    = (int2*)w;                    w += sizeof(int2) * (size_t)N_EDGES;   // 12.8 MB
    bf16*  Wp2    = (bf16*)w;                    w += sizeof(bf16) * 8 * 4 * 64 * 8;    // 32 KB
    bf16*  Wp3    = (bf16*)w;                    w += sizeof(bf16) * 8 * 4 * 64 * 8;    // 32 KB
    bf16*  Wp1    = (bf16*)w;                    w += sizeof(bf16) * 8 * 64 * 8;        // 8 KB
    bf16*  xp     = (bf16*)w;                    w += sizeof(bf16) * (size_t)N_NODES * 8; // 1.6 MB
    bf16*  A      = (bf16*)w;                    w += sizeof(bf16) * (size_t)N_NODES * HID; // 25.6 MB
    bf16*  B      = (bf16*)w;                    w += sizeof(bf16) * (size_t)N_NODES * HID; // 25.6 MB
    float* pool   = (float*)w;                   w += sizeof(float) * N_GRAPHS * HID;
    float* cnt    = (float*)w;                   w += sizeof(float) * N_GRAPHS;
    int*   rowptr = (int*)w;                     w += sizeof(int) * (N_NODES + 1);
    int*   gcnt   = (int*)w;                     w += sizeof(int) * NBKT;
    int*   bstart = (int*)w;                     w += sizeof(int) * NBKT;
    int*   bcur   = (int*)w;                     w += sizeof(int) * NBKT;

    // partition temporaries alias A (25.6 MB >= 12.8 + 6.4); A is first written
    // by layer1_fused, strictly after bucket_sort on the same stream.
    int2* tmp2 = (int2*)A;
    int*  tmpd = (int*)((char*)A + sizeof(int2) * (size_t)N_EDGES);

    // ---- CSR build v2 + packs (10 dispatches total) ----
    hipMemsetAsync(gcnt, 0, sizeof(int) * NBKT, stream);
    bucket_hist<<<(N_EDGES + TILE - 1) / TILE, 256, 0, stream>>>(dst, gcnt);
    pack_all<<<18 + (N_NODES + 255) / 256, 256, 0, stream>>>(W2, W3, W1, x, Wp2, Wp3, Wp1, xp);
    scan_buckets<<<1, 256, 0, stream>>>(gcnt, bstart, bcur, rowptr, pool);
    partition_kernel<<<(N_EDGES + TILE - 1) / TILE, 256, 0, stream>>>(src, dst, ea, bcur, tmp2, tmpd);
    bucket_sort<<<NBKT, 512, 0, stream>>>(tmp2, tmpd, bstart, gcnt, rowptr, csr);

    // ---- Layer 1 (fused gather + MFMA, packed x) ----
    layer1_fused<<<N_NODES / NPB, 256, 0, stream>>>(xp, csr, rowptr, We1, be1, Wp1, b1, A);

    // ---- Layer 2: A -> B ----
    hidden_layer<0><<<N_NODES / NPB, 256, 0, stream>>>(A, csr, rowptr, We2, be2, Wp2, b2, B,
                                                       batch, nullptr, nullptr);

    // ---- Layer 3: B -> pool (register pool accum, no h3 write) ----
    hidden_layer<1><<<N_NODES / NPB, 256, 0, stream>>>(B, csr, rowptr, We3, be3, Wp3, b3, nullptr,
                                                       batch, pool, cnt);

    // ---- Head ----
    final_kernel<<<1, 64, 0, stream>>>(pool, cnt, Wlin, blin, (float*)d_out);
}

// Round 18
// 354.637 us; speedup vs baseline: 1.1617x; 1.0839x over previous
//
#include <hip/hip_runtime.h>
#include <hip/hip_bf16.h>

#define N_NODES 100000
#define N_EDGES 1600000
#define N_FEAT 7
#define HID 128
#define N_CLASS 5
#define N_GRAPHS 8
#define NPB 16  // nodes per block in fused layer kernels (grid 6250, 4 waves x 4 nodes)
#define TLP 136  // padded LDS row (bf16 elems): 272 B stride
#define TLP1 40  // layer-1 padded LDS row (K=32 zero-padded + 8)
#define NBKT 196       // ceil(N_NODES / 512) dst-buckets
#define BKT_SHIFT 9    // 512-node buckets
#define TILE 4096      // edges per partition block
#define NSLICE 32      // pool accumulator slices (bid&31 -> XCD-consistent)

typedef __hip_bfloat16 bf16;
typedef __attribute__((ext_vector_type(8))) short short8;   // 8 bf16 (4 VGPRs)
typedef __attribute__((ext_vector_type(4))) float f32x4;    // MFMA accumulator

// ---------------- CSR build v2 (r15-verified) ----------------

__global__ __launch_bounds__(256) void bucket_hist(const int* __restrict__ dst,
                                                   int* __restrict__ gcnt) {
    __shared__ int l[NBKT];
    int tid = threadIdx.x;
    for (int i = tid; i < NBKT; i += 256) l[i] = 0;
    __syncthreads();
    int e0 = blockIdx.x * TILE;
    int ne = N_EDGES - e0; if (ne > TILE) ne = TILE;
    for (int t = tid; t < ne; t += 256)
        atomicAdd(&l[dst[e0 + t] >> BKT_SHIFT], 1);
    __syncthreads();
    for (int i = tid; i < NBKT; i += 256)
        if (l[i]) atomicAdd(&gcnt[i], l[i]);
}

// 1 block: exclusive-scan bucket counts -> bstart/bcur; zero sliced pool+cnt;
// set rowptr[N].
__global__ __launch_bounds__(256) void scan_buckets(const int* __restrict__ gcnt,
                                                    int* __restrict__ bstart,
                                                    int* __restrict__ bcur,
                                                    int* __restrict__ rowptr,
                                                    float* __restrict__ poolS) {
    __shared__ int s[256];
    int tid = threadIdx.x;
    int v = (tid < NBKT) ? gcnt[tid] : 0;
    s[tid] = v;
    __syncthreads();
    for (int o = 1; o < 256; o <<= 1) {
        int u = (tid >= o) ? s[tid - o] : 0;
        __syncthreads();
        s[tid] += u;
        __syncthreads();
    }
    if (tid < NBKT) { bstart[tid] = s[tid] - v; bcur[tid] = s[tid] - v; }
    if (tid == 0) rowptr[N_NODES] = N_EDGES;
    for (int i = tid; i < NSLICE * (N_GRAPHS * HID + N_GRAPHS); i += 256) poolS[i] = 0.f;
}

// Pass A: LDS counting-sort each edge tile by dst-bucket, write bucket-major.
__global__ __launch_bounds__(256) void partition_kernel(
        const int* __restrict__ src, const int* __restrict__ dst,
        const float* __restrict__ ea, int* __restrict__ bcur,
        int2* __restrict__ tmp2, int* __restrict__ tmpd) {
    __shared__ int lsrc[TILE], lea[TILE], ldst[TILE];   // 48 KB
    __shared__ int cnt[NBKT], gbase[NBKT];
    __shared__ int off[256];
    int tid = threadIdx.x;
    int e0 = blockIdx.x * TILE;
    int nedge = N_EDGES - e0; if (nedge > TILE) nedge = TILE;

    for (int bkt = tid; bkt < NBKT; bkt += 256) cnt[bkt] = 0;
    __syncthreads();
    for (int t = tid; t < nedge; t += 256)
        atomicAdd(&cnt[dst[e0 + t] >> BKT_SHIFT], 1);
    __syncthreads();
    off[tid] = (tid < NBKT) ? cnt[tid] : 0;
    __syncthreads();
    for (int o = 1; o < 256; o <<= 1) {                  // Hillis-Steele inclusive
        int u = (tid >= o) ? off[tid - o] : 0;
        __syncthreads();
        off[tid] += u;
        __syncthreads();
    }
    if (tid < NBKT) {
        off[tid] -= cnt[tid];                            // inclusive -> exclusive
        gbase[tid] = atomicAdd(&bcur[tid], cnt[tid]);    // reserve global bucket range
    }
    __syncthreads();
    if (tid < NBKT) cnt[tid] = 0;                        // reuse as rank counter
    __syncthreads();
    for (int t = tid; t < nedge; t += 256) {
        int d = dst[e0 + t];
        int bkt = d >> BKT_SHIFT;
        int sp = off[bkt] + atomicAdd(&cnt[bkt], 1);     // sorted slot in tile
        lsrc[sp] = src[e0 + t];
        lea[sp] = __float_as_int(ea[e0 + t]);
        ldst[sp] = d;
    }
    __syncthreads();
    for (int t = tid; t < nedge; t += 256) {             // bucket-grouped writeout
        int d = ldst[t];
        int bkt = d >> BKT_SHIFT;
        int gi = gbase[bkt] + (t - off[bkt]);
        tmp2[gi] = make_int2(lsrc[t], lea[t]);
        tmpd[gi] = d;
    }
}

// Pass B: one block per bucket. LDS per-node hist + scan -> rowptr segment;
// then scatter csr within the bucket's own ~100KB window.
__global__ __launch_bounds__(512) void bucket_sort(
        const int2* __restrict__ tmp2, const int* __restrict__ tmpd,
        const int* __restrict__ bstart, const int* __restrict__ gcnt,
        int* __restrict__ rowptr, int2* __restrict__ csr) {
    __shared__ int s[512];
    __shared__ int lcur[512];
    int tid = threadIdx.x;
    int b = blockIdx.x;
    int nb0 = b << BKT_SHIFT;
    int r0 = bstart[b];
    int r1 = r0 + gcnt[b];
    s[tid] = 0;
    __syncthreads();
    for (int i = r0 + tid; i < r1; i += 512)
        atomicAdd(&s[tmpd[i] - nb0], 1);
    __syncthreads();
    int v = s[tid];
    for (int o = 1; o < 512; o <<= 1) {                  // inclusive scan
        int u = (tid >= o) ? s[tid - o] : 0;
        __syncthreads();
        s[tid] += u;
        __syncthreads();
    }
    int excl = s[tid] - v;
    lcur[tid] = excl;
    int n = nb0 + tid;
    if (n < N_NODES) rowptr[n] = r0 + excl;
    __syncthreads();
    for (int i = r0 + tid; i < r1; i += 512) {
        int d = tmpd[i];
        int p = r0 + atomicAdd(&lcur[d - nb0], 1);
        csr[p] = tmp2[i];
    }
}

// ---------------- merged pre-pack: Wp2, Wp3, Wp1, xp in one launch ----------------
// B-frag for mfma_f32_16x16x32_bf16: lane l holds B[k=(l>>4)*8+q][col=l&15].

__device__ __forceinline__ void pack_w_body(const float* W, bf16* Wp, int t) {
    int l = t & 63;
    int kk = (t >> 6) & 3;
    int jt = t >> 8;
    int kbase = kk * 32 + (l >> 4) * 8;
    int j = jt * 16 + (l & 15);
#pragma unroll
    for (int q = 0; q < 8; ++q)
        Wp[t * 8 + q] = __float2bfloat16(W[(kbase + q) * HID + j]);
}

__global__ __launch_bounds__(256) void pack_all(
        const float* __restrict__ W2, const float* __restrict__ W3,
        const float* __restrict__ W1, const float* __restrict__ x,
        bf16* __restrict__ Wp2, bf16* __restrict__ Wp3,
        bf16* __restrict__ Wp1, bf16* __restrict__ xp) {
    int bid = blockIdx.x, tid = threadIdx.x;
    if (bid < 8) {
        pack_w_body(W2, Wp2, bid * 256 + tid);
    } else if (bid < 16) {
        pack_w_body(W3, Wp3, (bid - 8) * 256 + tid);
    } else if (bid < 18) {
        int t = (bid - 16) * 256 + tid;          // 0..511: K=7 zero-padded to 32
        if (t < 512) {
            int l = t & 63;
            int jt = t >> 6;
            int j = jt * 16 + (l & 15);
#pragma unroll
            for (int q = 0; q < 8; ++q) {
                int k = (l >> 4) * 8 + q;
                Wp1[t * 8 + q] = __float2bfloat16(k < N_FEAT ? W1[k * HID + j] : 0.f);
            }
        }
    } else {
        int n = (bid - 18) * 256 + tid;          // x: fp32 [N][7] -> bf16 [N][8]
        if (n < N_NODES) {
            unsigned short pk[8];
#pragma unroll
            for (int k = 0; k < N_FEAT; ++k) {
                bf16 h = __float2bfloat16(x[n * N_FEAT + k]);
                pk[k] = *(unsigned short*)&h;
            }
            pk[7] = 0;
            *(uint4*)&xp[(size_t)n * 8] = *(const uint4*)pk;
        }
    }
}

// ---------------- Fused layer 1: gather(xp, in=7) + MFMA ----------------
__global__ __launch_bounds__(256) void layer1_fused(
        const bf16* __restrict__ xp, const int2* __restrict__ csr,
        const int* __restrict__ rowptr, const float* __restrict__ We,
        const float* __restrict__ be, const bf16* __restrict__ Wp1,
        const float* __restrict__ b, bf16* __restrict__ hout) {
    __shared__ __align__(16) unsigned short tl[NPB][TLP1];   // 1.28 KB
    int tid = threadIdx.x;
    int wave = tid >> 6;
    int lane = tid & 63;
    int sub = lane >> 4;
    int l = lane & 15;
    int n0 = blockIdx.x * NPB;

    for (int i = tid; i < NPB * TLP1; i += 256) ((unsigned short*)tl)[i] = 0;

    float we[N_FEAT], bee[N_FEAT], p[N_FEAT];
#pragma unroll
    for (int k = 0; k < N_FEAT; ++k) { we[k] = We[k]; bee[k] = be[k]; p[k] = 0.f; }
    __syncthreads();   // zero-init visible before lane-0 t-writes

    const uint4* xp4 = (const uint4*)xp;
    int m = wave * 4 + sub;
    int n = n0 + m;
    int r0 = rowptr[n], r1 = rowptr[n + 1];
    for (int i = r0 + l; i < r1; i += 16) {
        int2 sa = csr[i];
        float a = __int_as_float(sa.y);
        uint4 rv = xp4[sa.x];                        // whole 7-feat row, one load
#pragma unroll
        for (int p_ = 0; p_ < 4; ++p_) {
            unsigned u = ((const unsigned*)&rv)[p_];
            float f0 = __uint_as_float(u << 16);
            float m0 = f0 + a * we[2 * p_] + bee[2 * p_];
            p[2 * p_] += m0 > 0.f ? m0 : 0.f;
            if (2 * p_ + 1 < N_FEAT) {
                float f1 = __uint_as_float(u & 0xffff0000u);
                float m1 = f1 + a * we[2 * p_ + 1] + bee[2 * p_ + 1];
                p[2 * p_ + 1] += m1 > 0.f ? m1 : 0.f;
            }
        }
    }
#pragma unroll
    for (int off = 8; off >= 1; off >>= 1)
#pragma unroll
        for (int k = 0; k < N_FEAT; ++k)
            p[k] += __shfl_xor(p[k], off, 16);
    if (l == 0) {
        uint4 sv = xp4[n];
#pragma unroll
        for (int k = 0; k < N_FEAT; ++k) {
            unsigned u = ((const unsigned*)&sv)[k >> 1];
            float fs = __uint_as_float((k & 1) ? (u & 0xffff0000u) : (u << 16));
            bf16 hb = __float2bfloat16(p[k] + fs);
            tl[m][k] = *(unsigned short*)&hb;
        }
    }
    __syncthreads();

    // MFMA node-update: one k-step (K=32, k>=7 are zeros)
    // Verified mapping (m89): A lane l: row=l&15, k=(l>>4)*8+q;
    //                         B lane l: col=l&15, k=(l>>4)*8+q;
    //                         D lane l: col=l&15, row=(l>>4)*4+reg.
    int c = lane & 15;
    int kq = lane >> 4;
    int jt0 = wave * 2, jt1 = jt0 + 1;
    f32x4 d0 = {0.f, 0.f, 0.f, 0.f}, d1 = {0.f, 0.f, 0.f, 0.f};
    const short8* wp = (const short8*)Wp1;
    short8 aF = *(const short8*)&tl[c][kq * 8];
    short8 b0 = wp[jt0 * 64 + lane];
    short8 b1 = wp[jt1 * 64 + lane];
    d0 = __builtin_amdgcn_mfma_f32_16x16x32_bf16(aF, b0, d0, 0, 0, 0);
    d1 = __builtin_amdgcn_mfma_f32_16x16x32_bf16(aF, b1, d1, 0, 0, 0);
    float bv0 = b[jt0 * 16 + c];
    float bv1 = b[jt1 * 16 + c];
#pragma unroll
    for (int i = 0; i < 4; ++i) {
        int mm = kq * 4 + i;
        size_t base = (size_t)(n0 + mm) * HID;
        float v0 = d0[i] + bv0;
        float v1 = d1[i] + bv1;
        hout[base + jt0 * 16 + c] = __float2bfloat16(v0 > 0.f ? v0 : 0.f);
        hout[base + jt1 * 16 + c] = __float2bfloat16(v1 > 0.f ? v1 : 0.f);
    }
}

// ---------------- Fused hidden layer + optional pooling epilogue ----------------
// POOL=0: write bf16 hout rows. POOL=1 (layer 3): skip the 25.6 MB hout write;
// register pool accum (r17) + SLICED global accumulators (r17 counters: VALU
// cycles identical, +35us = end-of-kernel atomic drain -- ~780 blocks/graph
// hammering the SAME 128 pool addresses => ~780-deep serial RMW chains; waves
// hold occupancy until vmcnt(0) drains). poolS[32] slices, slice=bid&31
// (consistent with XCD=bid&7 -> slice is XCD-local): chain depth 780 -> ~24.
// hout MUST differ from hin (POOL=0).
template<int POOL>
__global__ __launch_bounds__(256) void hidden_layer(
        const bf16* __restrict__ hin, const int2* __restrict__ csr,
        const int* __restrict__ rowptr, const float* __restrict__ We,
        const float* __restrict__ be, const bf16* __restrict__ Wp,
        const float* __restrict__ b, bf16* __restrict__ hout,
        const int* __restrict__ batch, float* __restrict__ poolS,
        float* __restrict__ cntS) {
    __shared__ __align__(16) unsigned short tl[NPB][TLP];   // bf16 bits, 4.3 KB
    __shared__ int bb[NPB];                                  // 64 B (POOL only)
    int tid = threadIdx.x;
    int wave = tid >> 6;
    int lane = tid & 63;
    int el = lane >> 4;          // edge slot 0..3
    int fc = lane & 15;          // feature chunk: feats fc*8 .. fc*8+7
    int n0 = blockIdx.x * NPB;

    if (POOL && tid < NPB) bb[tid] = batch[n0 + tid];

    float we8[8], be8[8];
#pragma unroll
    for (int q = 0; q < 8; ++q) {
        we8[q] = We[fc * 8 + q];
        be8[q] = be[fc * 8 + q];
    }

    const uint4* hin4 = (const uint4*)hin;   // one 128-feat bf16 row = 16 uint4

    for (int loc = 0; loc < 4; ++loc) {
        int m = wave * 4 + loc;
        int n = n0 + m;
        int r0 = rowptr[n], r1 = rowptr[n + 1];
        float acc[8];
#pragma unroll
        for (int q = 0; q < 8; ++q) acc[q] = 0.f;
#pragma unroll 2
        for (int i = r0 + el; i < r1; i += 4) {
            int2 sa = csr[i];
            int s = sa.x;
            float a = __int_as_float(sa.y);
            uint4 rv = hin4[(size_t)s * 16 + fc];
#pragma unroll
            for (int p = 0; p < 4; ++p) {
                unsigned u = ((const unsigned*)&rv)[p];
                float f0 = __uint_as_float(u << 16);          // low bf16
                float f1 = __uint_as_float(u & 0xffff0000u);  // high bf16
                float m0 = f0 + a * we8[2 * p] + be8[2 * p];
                float m1 = f1 + a * we8[2 * p + 1] + be8[2 * p + 1];
                acc[2 * p]     += m0 > 0.f ? m0 : 0.f;
                acc[2 * p + 1] += m1 > 0.f ? m1 : 0.f;
            }
        }
        // combine the 4 edge slots (lanes l, l^16, l^32 share fc)
#pragma unroll
        for (int q = 0; q < 8; ++q) {
            acc[q] += __shfl_xor(acc[q], 16, 64);
            acc[q] += __shfl_xor(acc[q], 32, 64);
        }
        if (el == 0) {
            uint4 sv = hin4[(size_t)n * 16 + fc];
            unsigned short pk[8];
#pragma unroll
            for (int p = 0; p < 4; ++p) {
                unsigned u = ((const unsigned*)&sv)[p];
                float v0 = acc[2 * p]     + __uint_as_float(u << 16);
                float v1 = acc[2 * p + 1] + __uint_as_float(u & 0xffff0000u);
                bf16 h0 = __float2bfloat16(v0);
                bf16 h1 = __float2bfloat16(v1);
                pk[2 * p]     = *(unsigned short*)&h0;
                pk[2 * p + 1] = *(unsigned short*)&h1;
            }
            *(uint4*)&tl[m][fc * 8] = *(const uint4*)pk;   // one ds_write_b128
        }
    }
    __syncthreads();   // orders bb load + tl writes

    // MFMA node-update: out[m][j] = relu(b[j] + sum_k t[m][k] * W[k][j])
    // Verified mapping (m89): A lane l: row=l&15, k=(l>>4)*8+q;
    //                         B lane l: col=l&15, k=(l>>4)*8+q;
    //                         D lane l: col=l&15, row=(l>>4)*4+reg.
    int c = lane & 15;           // A row / D col
    int kq = lane >> 4;          // k-chunk selector
    int jt0 = wave * 2, jt1 = jt0 + 1;
    f32x4 d0 = {0.f, 0.f, 0.f, 0.f}, d1 = {0.f, 0.f, 0.f, 0.f};
    const short8* wp = (const short8*)Wp;
#pragma unroll
    for (int kk = 0; kk < 4; ++kk) {
        short8 a  = *(const short8*)&tl[c][kk * 32 + kq * 8];
        short8 b0 = wp[(jt0 * 4 + kk) * 64 + lane];
        short8 b1 = wp[(jt1 * 4 + kk) * 64 + lane];
        d0 = __builtin_amdgcn_mfma_f32_16x16x32_bf16(a, b0, d0, 0, 0, 0);
        d1 = __builtin_amdgcn_mfma_f32_16x16x32_bf16(a, b1, d1, 0, 0, 0);
    }
    float bv0 = b[jt0 * 16 + c];
    float bv1 = b[jt1 * 16 + c];

    if (POOL) {
        int slice = blockIdx.x & (NSLICE - 1);
        float* gp = poolS + (size_t)slice * N_GRAPHS * HID;
        int gmin = bb[0], gmax = bb[NPB - 1];       // batch sorted
        float pg[2][2] = {{0.f, 0.f}, {0.f, 0.f}};  // [graph slot][j slot]
#pragma unroll
        for (int i = 0; i < 4; ++i) {
            int m = kq * 4 + i;
            float v0 = d0[i] + bv0;
            float v1 = d1[i] + bv1;
            v0 = v0 > 0.f ? v0 : 0.f;
            v1 = v1 > 0.f ? v1 : 0.f;
            if (bb[m] == gmin) { pg[0][0] += v0; pg[0][1] += v1; }
            else               { pg[1][0] += v0; pg[1][1] += v1; }
        }
        // reduce over kq: lanes {c, c+16, c+32, c+48}
#pragma unroll
        for (int s = 0; s < 2; ++s)
#pragma unroll
            for (int t = 0; t < 2; ++t) {
                pg[s][t] += __shfl_xor(pg[s][t], 16, 64);
                pg[s][t] += __shfl_xor(pg[s][t], 32, 64);
            }
        if (lane < 16) {
            atomicAdd(&gp[gmin * HID + jt0 * 16 + c], pg[0][0]);
            atomicAdd(&gp[gmin * HID + jt1 * 16 + c], pg[0][1]);
            if (gmax != gmin) {
                atomicAdd(&gp[gmax * HID + jt0 * 16 + c], pg[1][0]);
                atomicAdd(&gp[gmax * HID + jt1 * 16 + c], pg[1][1]);
            }
        }
        if (tid == 0) {
            float* gc = cntS + slice * N_GRAPHS;
            int cg = bb[0], cc = 0;
#pragma unroll
            for (int i = 0; i < NPB; ++i) {
                int g = bb[i];
                if (g != cg) { atomicAdd(&gc[cg], (float)cc); cg = g; cc = 0; }
                cc++;
            }
            atomicAdd(&gc[cg], (float)cc);
        }
    } else {
#pragma unroll
        for (int i = 0; i < 4; ++i) {
            int m = kq * 4 + i;
            size_t base = (size_t)(n0 + m) * HID;
            float v0 = d0[i] + bv0;
            float v1 = d1[i] + bv1;
            hout[base + jt0 * 16 + c] = __float2bfloat16(v0 > 0.f ? v0 : 0.f);
            hout[base + jt1 * 16 + c] = __float2bfloat16(v1 > 0.f ? v1 : 0.f);
        }
    }
}

// ---------------- Head: reduce slices + linear ----------------

__global__ __launch_bounds__(256) void final_kernel(
        const float* __restrict__ poolS, const float* __restrict__ cntS,
        const float* __restrict__ Wlin, const float* __restrict__ blin,
        float* __restrict__ out) {
    __shared__ float pl[N_GRAPHS * HID];
    __shared__ float cs[N_GRAPHS];
    int tid = threadIdx.x;
    for (int i = tid; i < N_GRAPHS * HID; i += 256) {
        float s = 0.f;
        for (int sl = 0; sl < NSLICE; ++sl) s += poolS[(size_t)sl * N_GRAPHS * HID + i];
        pl[i] = s;
    }
    if (tid < N_GRAPHS) {
        float s = 0.f;
        for (int sl = 0; sl < NSLICE; ++sl) s += cntS[sl * N_GRAPHS + tid];
        cs[tid] = s;
    }
    __syncthreads();
    if (tid < N_GRAPHS * N_CLASS) {
        int g = tid / N_CLASS, c = tid % N_CLASS;
        float invc = 1.f / fmaxf(cs[g], 1.f);
        float acc = blin[c];
        for (int j = 0; j < HID; ++j) acc += pl[g * HID + j] * invc * Wlin[j * N_CLASS + c];
        out[tid] = acc;
    }
}

extern "C" void kernel_launch(void* const* d_in, const int* in_sizes, int n_in,
                              void* d_out, int out_size, void* d_ws, size_t ws_size,
                              hipStream_t stream) {
    const float* x    = (const float*)d_in[0];
    const int*   ei   = (const int*)d_in[1];
    const float* ea   = (const float*)d_in[2];
    const int*   batch= (const int*)d_in[3];
    const float* We1  = (const float*)d_in[4];
    const float* be1  = (const float*)d_in[5];
    const float* W1   = (const float*)d_in[6];
    const float* b1   = (const float*)d_in[7];
    const float* We2  = (const float*)d_in[8];
    const float* be2  = (const float*)d_in[9];
    const float* W2   = (const float*)d_in[10];
    const float* b2   = (const float*)d_in[11];
    const float* We3  = (const float*)d_in[12];
    const float* be3  = (const float*)d_in[13];
    const float* W3   = (const float*)d_in[14];
    const float* b3   = (const float*)d_in[15];
    const float* Wlin = (const float*)d_in[16];
    const float* blin = (const float*)d_in[17];

    const int* src = ei;
    const int* dst = ei + N_EDGES;

    // workspace layout (csr first: 16B-aligned at base)
    char* w = (char*)d_ws;
    int2*  csr    = (int2*)w;                    w += sizeof(int2) * (size_t)N_EDGES;   // 12.8 MB
    bf16*  Wp2    = (bf16*)w;                    w += sizeof(bf16) * 8 * 4 * 64 * 8;    // 32 KB
    bf16*  Wp3    = (bf16*)w;                    w += sizeof(bf16) * 8 * 4 * 64 * 8;    // 32 KB
    bf16*  Wp1    = (bf16*)w;                    w += sizeof(bf16) * 8 * 64 * 8;        // 8 KB
    bf16*  xp     = (bf16*)w;                    w += sizeof(bf16) * (size_t)N_NODES * 8; // 1.6 MB
    bf16*  A      = (bf16*)w;                    w += sizeof(bf16) * (size_t)N_NODES * HID; // 25.6 MB
    bf16*  B      = (bf16*)w;                    w += sizeof(bf16) * (size_t)N_NODES * HID; // 25.6 MB
    float* poolS  = (float*)w;                   w += sizeof(float) * NSLICE * N_GRAPHS * HID; // 128 KB
    float* cntS   = (float*)w;                   w += sizeof(float) * NSLICE * N_GRAPHS;
    int*   rowptr = (int*)w;                     w += sizeof(int) * (N_NODES + 1);
    int*   gcnt   = (int*)w;                     w += sizeof(int) * NBKT;
    int*   bstart = (int*)w;                     w += sizeof(int) * NBKT;
    int*   bcur   = (int*)w;                     w += sizeof(int) * NBKT;

    // partition temporaries alias A (25.6 MB >= 12.8 + 6.4); A is first written
    // by layer1_fused, strictly after bucket_sort on the same stream.
    int2* tmp2 = (int2*)A;
    int*  tmpd = (int*)((char*)A + sizeof(int2) * (size_t)N_EDGES);

    // ---- CSR build v2 + packs (10 dispatches total) ----
    hipMemsetAsync(gcnt, 0, sizeof(int) * NBKT, stream);
    bucket_hist<<<(N_EDGES + TILE - 1) / TILE, 256, 0, stream>>>(dst, gcnt);
    pack_all<<<18 + (N_NODES + 255) / 256, 256, 0, stream>>>(W2, W3, W1, x, Wp2, Wp3, Wp1, xp);
    scan_buckets<<<1, 256, 0, stream>>>(gcnt, bstart, bcur, rowptr, poolS);
    partition_kernel<<<(N_EDGES + TILE - 1) / TILE, 256, 0, stream>>>(src, dst, ea, bcur, tmp2, tmpd);
    bucket_sort<<<NBKT, 512, 0, stream>>>(tmp2, tmpd, bstart, gcnt, rowptr, csr);

    // ---- Layer 1 (fused gather + MFMA, packed x) ----
    layer1_fused<<<N_NODES / NPB, 256, 0, stream>>>(xp, csr, rowptr, We1, be1, Wp1, b1, A);

    // ---- Layer 2: A -> B ----
    hidden_layer<0><<<N_NODES / NPB, 256, 0, stream>>>(A, csr, rowptr, We2, be2, Wp2, b2, B,
                                                       batch, nullptr, nullptr);

    // ---- Layer 3: B -> sliced pool (register accum, no h3 write) ----
    hidden_layer<1><<<N_NODES / NPB, 256, 0, stream>>>(B, csr, rowptr, We3, be3, Wp3, b3, nullptr,
                                                       batch, poolS, cntS);

    // ---- Head (slice reduce + linear) ----
    final_kernel<<<1, 256, 0, stream>>>(poolS, cntS, Wlin, blin, (float*)d_out);
}

// Round 21
// 351.920 us; speedup vs baseline: 1.1706x; 1.0077x over previous
//
#include <hip/hip_runtime.h>
#include <hip/hip_bf16.h>

#define N_NODES 100000
#define N_EDGES 1600000
#define N_FEAT 7
#define HID 128
#define N_CLASS 5
#define N_GRAPHS 8
#define NPB 16  // nodes per block in fused layer kernels (grid 6250, 4 waves x 4 nodes)
#define TLP 136  // padded LDS row (bf16 elems): 272 B stride
#define TLP1 40  // layer-1 padded LDS row (K=32 zero-padded + 8)
#define NBKT 196       // ceil(N_NODES / 512) dst-buckets
#define BKT_SHIFT 9    // 512-node buckets
#define TILE 4096      // edges per partition block
#define NHTILE ((N_EDGES + TILE - 1) / TILE)   // 391 hist/partition tiles
#define NSLICE 32      // pool accumulator slices (bid&31 -> XCD-consistent)

typedef __hip_bfloat16 bf16;
typedef __attribute__((ext_vector_type(8))) short short8;   // 8 bf16 (4 VGPRs)
typedef __attribute__((ext_vector_type(4))) float f32x4;    // MFMA accumulator

// ---------------- merged prologue: packs + bucket histogram in ONE launch ----------------
// bids [0,18+391): pack Wp2/Wp3/Wp1/xp; bids [409, 409+391): bucket_hist tiles.
// All inputs read-only, outputs disjoint -> safe to fuse; saves a dispatch
// boundary and hides the small pack work under hist's 6.4 MB read.

__device__ __forceinline__ void pack_w_body(const float* W, bf16* Wp, int t) {
    int l = t & 63;
    int kk = (t >> 6) & 3;
    int jt = t >> 8;
    int kbase = kk * 32 + (l >> 4) * 8;
    int j = jt * 16 + (l & 15);
#pragma unroll
    for (int q = 0; q < 8; ++q)
        Wp[t * 8 + q] = __float2bfloat16(W[(kbase + q) * HID + j]);
}

#define XP_BLKS ((N_NODES + 255) / 256)   // 391

__global__ __launch_bounds__(256) void prologue_kernel(
        const float* __restrict__ W2, const float* __restrict__ W3,
        const float* __restrict__ W1, const float* __restrict__ x,
        const int* __restrict__ dst,
        bf16* __restrict__ Wp2, bf16* __restrict__ Wp3,
        bf16* __restrict__ Wp1, bf16* __restrict__ xp,
        int* __restrict__ gcnt) {
    int bid = blockIdx.x, tid = threadIdx.x;
    if (bid < 8) {
        pack_w_body(W2, Wp2, bid * 256 + tid);
    } else if (bid < 16) {
        pack_w_body(W3, Wp3, (bid - 8) * 256 + tid);
    } else if (bid < 18) {
        int t = (bid - 16) * 256 + tid;          // 0..511: K=7 zero-padded to 32
        if (t < 512) {
            int l = t & 63;
            int jt = t >> 6;
            int j = jt * 16 + (l & 15);
#pragma unroll
            for (int q = 0; q < 8; ++q) {
                int k = (l >> 4) * 8 + q;
                Wp1[t * 8 + q] = __float2bfloat16(k < N_FEAT ? W1[k * HID + j] : 0.f);
            }
        }
    } else if (bid < 18 + XP_BLKS) {
        int n = (bid - 18) * 256 + tid;          // x: fp32 [N][7] -> bf16 [N][8]
        if (n < N_NODES) {
            unsigned short pk[8];
#pragma unroll
            for (int k = 0; k < N_FEAT; ++k) {
                bf16 h = __float2bfloat16(x[n * N_FEAT + k]);
                pk[k] = *(unsigned short*)&h;
            }
            pk[7] = 0;
            *(uint4*)&xp[(size_t)n * 8] = *(const uint4*)pk;
        }
    } else {
        // bucket histogram tile
        __shared__ int l[NBKT];
        int hb = bid - (18 + XP_BLKS);
        for (int i = tid; i < NBKT; i += 256) l[i] = 0;
        __syncthreads();
        int e0 = hb * TILE;
        int ne = N_EDGES - e0; if (ne > TILE) ne = TILE;
        for (int t = tid; t < ne; t += 256)
            atomicAdd(&l[dst[e0 + t] >> BKT_SHIFT], 1);
        __syncthreads();
        for (int i = tid; i < NBKT; i += 256)
            if (l[i]) atomicAdd(&gcnt[i], l[i]);
    }
}

// 1 block: exclusive-scan bucket counts -> bstart/bcur; zero sliced pool+cnt;
// set rowptr[N].
__global__ __launch_bounds__(256) void scan_buckets(const int* __restrict__ gcnt,
                                                    int* __restrict__ bstart,
                                                    int* __restrict__ bcur,
                                                    int* __restrict__ rowptr,
                                                    float* __restrict__ poolS) {
    __shared__ int s[256];
    int tid = threadIdx.x;
    int v = (tid < NBKT) ? gcnt[tid] : 0;
    s[tid] = v;
    __syncthreads();
    for (int o = 1; o < 256; o <<= 1) {
        int u = (tid >= o) ? s[tid - o] : 0;
        __syncthreads();
        s[tid] += u;
        __syncthreads();
    }
    if (tid < NBKT) { bstart[tid] = s[tid] - v; bcur[tid] = s[tid] - v; }
    if (tid == 0) rowptr[N_NODES] = N_EDGES;
    for (int i = tid; i < NSLICE * (N_GRAPHS * HID + N_GRAPHS); i += 256) poolS[i] = 0.f;
}

// Pass A: LDS counting-sort each edge tile by dst-bucket, write bucket-major.
__global__ __launch_bounds__(256) void partition_kernel(
        const int* __restrict__ src, const int* __restrict__ dst,
        const float* __restrict__ ea, int* __restrict__ bcur,
        int2* __restrict__ tmp2, int* __restrict__ tmpd) {
    __shared__ int lsrc[TILE], lea[TILE], ldst[TILE];   // 48 KB
    __shared__ int cnt[NBKT], gbase[NBKT];
    __shared__ int off[256];
    int tid = threadIdx.x;
    int e0 = blockIdx.x * TILE;
    int nedge = N_EDGES - e0; if (nedge > TILE) nedge = TILE;

    for (int bkt = tid; bkt < NBKT; bkt += 256) cnt[bkt] = 0;
    __syncthreads();
    for (int t = tid; t < nedge; t += 256)
        atomicAdd(&cnt[dst[e0 + t] >> BKT_SHIFT], 1);
    __syncthreads();
    off[tid] = (tid < NBKT) ? cnt[tid] : 0;
    __syncthreads();
    for (int o = 1; o < 256; o <<= 1) {                  // Hillis-Steele inclusive
        int u = (tid >= o) ? off[tid - o] : 0;
        __syncthreads();
        off[tid] += u;
        __syncthreads();
    }
    if (tid < NBKT) {
        off[tid] -= cnt[tid];                            // inclusive -> exclusive
        gbase[tid] = atomicAdd(&bcur[tid], cnt[tid]);    // reserve global bucket range
    }
    __syncthreads();
    if (tid < NBKT) cnt[tid] = 0;                        // reuse as rank counter
    __syncthreads();
    for (int t = tid; t < nedge; t += 256) {
        int d = dst[e0 + t];
        int bkt = d >> BKT_SHIFT;
        int sp = off[bkt] + atomicAdd(&cnt[bkt], 1);     // sorted slot in tile
        lsrc[sp] = src[e0 + t];
        lea[sp] = __float_as_int(ea[e0 + t]);
        ldst[sp] = d;
    }
    __syncthreads();
    for (int t = tid; t < nedge; t += 256) {             // bucket-grouped writeout
        int d = ldst[t];
        int bkt = d >> BKT_SHIFT;
        int gi = gbase[bkt] + (t - off[bkt]);
        tmp2[gi] = make_int2(lsrc[t], lea[t]);
        tmpd[gi] = d;
    }
}

// Pass B: one block per bucket. LDS per-node hist + scan -> rowptr segment;
// then scatter csr within the bucket's own ~100KB window.
__global__ __launch_bounds__(512) void bucket_sort(
        const int2* __restrict__ tmp2, const int* __restrict__ tmpd,
        const int* __restrict__ bstart, const int* __restrict__ gcnt,
        int* __restrict__ rowptr, int2* __restrict__ csr) {
    __shared__ int s[512];
    __shared__ int lcur[512];
    int tid = threadIdx.x;
    int b = blockIdx.x;
    int nb0 = b << BKT_SHIFT;
    int r0 = bstart[b];
    int r1 = r0 + gcnt[b];
    s[tid] = 0;
    __syncthreads();
    for (int i = r0 + tid; i < r1; i += 512)
        atomicAdd(&s[tmpd[i] - nb0], 1);
    __syncthreads();
    int v = s[tid];
    for (int o = 1; o < 512; o <<= 1) {                  // inclusive scan
        int u = (tid >= o) ? s[tid - o] : 0;
        __syncthreads();
        s[tid] += u;
        __syncthreads();
    }
    int excl = s[tid] - v;
    lcur[tid] = excl;
    int n = nb0 + tid;
    if (n < N_NODES) rowptr[n] = r0 + excl;
    __syncthreads();
    for (int i = r0 + tid; i < r1; i += 512) {
        int d = tmpd[i];
        int p = r0 + atomicAdd(&lcur[d - nb0], 1);
        csr[p] = tmp2[i];
    }
}

// ---------------- Fused layer 1: gather(xp, in=7) + MFMA ----------------
__global__ __launch_bounds__(256, 8) void layer1_fused(
        const bf16* __restrict__ xp, const int2* __restrict__ csr,
        const int* __restrict__ rowptr, const float* __restrict__ We,
        const float* __restrict__ be, const bf16* __restrict__ Wp1,
        const float* __restrict__ b, bf16* __restrict__ hout) {
    __shared__ __align__(16) unsigned short tl[NPB][TLP1];   // 1.28 KB
    int tid = threadIdx.x;
    int wave = tid >> 6;
    int lane = tid & 63;
    int sub = lane >> 4;
    int l = lane & 15;
    int n0 = blockIdx.x * NPB;

    for (int i = tid; i < NPB * TLP1; i += 256) ((unsigned short*)tl)[i] = 0;

    float we[N_FEAT], bee[N_FEAT], p[N_FEAT];
#pragma unroll
    for (int k = 0; k < N_FEAT; ++k) { we[k] = We[k]; bee[k] = be[k]; p[k] = 0.f; }
    __syncthreads();   // zero-init visible before lane-0 t-writes

    const uint4* xp4 = (const uint4*)xp;
    int m = wave * 4 + sub;
    int n = n0 + m;
    int r0 = rowptr[n], r1 = rowptr[n + 1];
    for (int i = r0 + l; i < r1; i += 16) {
        int2 sa = csr[i];
        float a = __int_as_float(sa.y);
        uint4 rv = xp4[sa.x];                        // whole 7-feat row, one load
#pragma unroll
        for (int p_ = 0; p_ < 4; ++p_) {
            unsigned u = ((const unsigned*)&rv)[p_];
            float f0 = __uint_as_float(u << 16);
            float m0 = f0 + a * we[2 * p_] + bee[2 * p_];
            p[2 * p_] += m0 > 0.f ? m0 : 0.f;
            if (2 * p_ + 1 < N_FEAT) {
                float f1 = __uint_as_float(u & 0xffff0000u);
                float m1 = f1 + a * we[2 * p_ + 1] + bee[2 * p_ + 1];
                p[2 * p_ + 1] += m1 > 0.f ? m1 : 0.f;
            }
        }
    }
#pragma unroll
    for (int off = 8; off >= 1; off >>= 1)
#pragma unroll
        for (int k = 0; k < N_FEAT; ++k)
            p[k] += __shfl_xor(p[k], off, 16);
    if (l == 0) {
        uint4 sv = xp4[n];
#pragma unroll
        for (int k = 0; k < N_FEAT; ++k) {
            unsigned u = ((const unsigned*)&sv)[k >> 1];
            float fs = __uint_as_float((k & 1) ? (u & 0xffff0000u) : (u << 16));
            bf16 hb = __float2bfloat16(p[k] + fs);
            tl[m][k] = *(unsigned short*)&hb;
        }
    }
    __syncthreads();

    // MFMA node-update: one k-step (K=32, k>=7 are zeros)
    // Verified mapping (m89): A lane l: row=l&15, k=(l>>4)*8+q;
    //                         B lane l: col=l&15, k=(l>>4)*8+q;
    //                         D lane l: col=l&15, row=(l>>4)*4+reg.
    int c = lane & 15;
    int kq = lane >> 4;
    int jt0 = wave * 2, jt1 = jt0 + 1;
    f32x4 d0 = {0.f, 0.f, 0.f, 0.f}, d1 = {0.f, 0.f, 0.f, 0.f};
    const short8* wp = (const short8*)Wp1;
    short8 aF = *(const short8*)&tl[c][kq * 8];
    short8 b0 = wp[jt0 * 64 + lane];
    short8 b1 = wp[jt1 * 64 + lane];
    d0 = __builtin_amdgcn_mfma_f32_16x16x32_bf16(aF, b0, d0, 0, 0, 0);
    d1 = __builtin_amdgcn_mfma_f32_16x16x32_bf16(aF, b1, d1, 0, 0, 0);
    float bv0 = b[jt0 * 16 + c];
    float bv1 = b[jt1 * 16 + c];
#pragma unroll
    for (int i = 0; i < 4; ++i) {
        int mm = kq * 4 + i;
        size_t base = (size_t)(n0 + mm) * HID;
        float v0 = d0[i] + bv0;
        float v1 = d1[i] + bv1;
        hout[base + jt0 * 16 + c] = __float2bfloat16(v0 > 0.f ? v0 : 0.f);
        hout[base + jt1 * 16 + c] = __float2bfloat16(v1 > 0.f ? v1 : 0.f);
    }
}

// ---------------- Fused hidden layer + optional pooling epilogue ----------------
// POOL=0: write bf16 hout rows. POOL=1 (layer 3): register pool accum + sliced
// global accumulators (r18-verified: 79us, matches POOL=0).
// hout MUST differ from hin (POOL=0).
template<int POOL>
__global__ __launch_bounds__(256, 8) void hidden_layer(
        const bf16* __restrict__ hin, const int2* __restrict__ csr,
        const int* __restrict__ rowptr, const float* __restrict__ We,
        const float* __restrict__ be, const bf16* __restrict__ Wp,
        const float* __restrict__ b, bf16* __restrict__ hout,
        const int* __restrict__ batch, float* __restrict__ poolS,
        float* __restrict__ cntS) {
    __shared__ __align__(16) unsigned short tl[NPB][TLP];   // bf16 bits, 4.3 KB
    __shared__ int bb[NPB];                                  // 64 B (POOL only)
    int tid = threadIdx.x;
    int wave = tid >> 6;
    int lane = tid & 63;
    int el = lane >> 4;          // edge slot 0..3
    int fc = lane & 15;          // feature chunk: feats fc*8 .. fc*8+7
    int n0 = blockIdx.x * NPB;

    if (POOL && tid < NPB) bb[tid] = batch[n0 + tid];

    float we8[8], be8[8];
#pragma unroll
    for (int q = 0; q < 8; ++q) {
        we8[q] = We[fc * 8 + q];
        be8[q] = be[fc * 8 + q];
    }

    const uint4* hin4 = (const uint4*)hin;   // one 128-feat bf16 row = 16 uint4

    for (int loc = 0; loc < 4; ++loc) {
        int m = wave * 4 + loc;
        int n = n0 + m;
        int r0 = rowptr[n], r1 = rowptr[n + 1];
        float acc[8];
#pragma unroll
        for (int q = 0; q < 8; ++q) acc[q] = 0.f;
#pragma unroll 2
        for (int i = r0 + el; i < r1; i += 4) {
            int2 sa = csr[i];
            int s = sa.x;
            float a = __int_as_float(sa.y);
            uint4 rv = hin4[(size_t)s * 16 + fc];
#pragma unroll
            for (int p = 0; p < 4; ++p) {
                unsigned u = ((const unsigned*)&rv)[p];
                float f0 = __uint_as_float(u << 16);          // low bf16
                float f1 = __uint_as_float(u & 0xffff0000u);  // high bf16
                float m0 = f0 + a * we8[2 * p] + be8[2 * p];
                float m1 = f1 + a * we8[2 * p + 1] + be8[2 * p + 1];
                acc[2 * p]     += m0 > 0.f ? m0 : 0.f;
                acc[2 * p + 1] += m1 > 0.f ? m1 : 0.f;
            }
        }
        // combine the 4 edge slots (lanes l, l^16, l^32 share fc)
#pragma unroll
        for (int q = 0; q < 8; ++q) {
            acc[q] += __shfl_xor(acc[q], 16, 64);
            acc[q] += __shfl_xor(acc[q], 32, 64);
        }
        if (el == 0) {
            uint4 sv = hin4[(size_t)n * 16 + fc];
            unsigned short pk[8];
#pragma unroll
            for (int p = 0; p < 4; ++p) {
                unsigned u = ((const unsigned*)&sv)[p];
                float v0 = acc[2 * p]     + __uint_as_float(u << 16);
                float v1 = acc[2 * p + 1] + __uint_as_float(u & 0xffff0000u);
                bf16 h0 = __float2bfloat16(v0);
                bf16 h1 = __float2bfloat16(v1);
                pk[2 * p]     = *(unsigned short*)&h0;
                pk[2 * p + 1] = *(unsigned short*)&h1;
            }
            *(uint4*)&tl[m][fc * 8] = *(const uint4*)pk;   // one ds_write_b128
        }
    }
    __syncthreads();   // orders bb load + tl writes

    // MFMA node-update: out[m][j] = relu(b[j] + sum_k t[m][k] * W[k][j])
    // Verified mapping (m89): A lane l: row=l&15, k=(l>>4)*8+q;
    //                         B lane l: col=l&15, k=(l>>4)*8+q;
    //                         D lane l: col=l&15, row=(l>>4)*4+reg.
    int c = lane & 15;           // A row / D col
    int kq = lane >> 4;          // k-chunk selector
    int jt0 = wave * 2, jt1 = jt0 + 1;
    f32x4 d0 = {0.f, 0.f, 0.f, 0.f}, d1 = {0.f, 0.f, 0.f, 0.f};
    const short8* wp = (const short8*)Wp;
#pragma unroll
    for (int kk = 0; kk < 4; ++kk) {
        short8 a  = *(const short8*)&tl[c][kk * 32 + kq * 8];
        short8 b0 = wp[(jt0 * 4 + kk) * 64 + lane];
        short8 b1 = wp[(jt1 * 4 + kk) * 64 + lane];
        d0 = __builtin_amdgcn_mfma_f32_16x16x32_bf16(a, b0, d0, 0, 0, 0);
        d1 = __builtin_amdgcn_mfma_f32_16x16x32_bf16(a, b1, d1, 0, 0, 0);
    }
    float bv0 = b[jt0 * 16 + c];
    float bv1 = b[jt1 * 16 + c];

    if (POOL) {
        int slice = blockIdx.x & (NSLICE - 1);
        float* gp = poolS + (size_t)slice * N_GRAPHS * HID;
        int gmin = bb[0], gmax = bb[NPB - 1];       // batch sorted
        float pg[2][2] = {{0.f, 0.f}, {0.f, 0.f}};  // [graph slot][j slot]
#pragma unroll
        for (int i = 0; i < 4; ++i) {
            int m = kq * 4 + i;
            float v0 = d0[i] + bv0;
            float v1 = d1[i] + bv1;
            v0 = v0 > 0.f ? v0 : 0.f;
            v1 = v1 > 0.f ? v1 : 0.f;
            if (bb[m] == gmin) { pg[0][0] += v0; pg[0][1] += v1; }
            else               { pg[1][0] += v0; pg[1][1] += v1; }
        }
        // reduce over kq: lanes {c, c+16, c+32, c+48}
#pragma unroll
        for (int s = 0; s < 2; ++s)
#pragma unroll
            for (int t = 0; t < 2; ++t) {
                pg[s][t] += __shfl_xor(pg[s][t], 16, 64);
                pg[s][t] += __shfl_xor(pg[s][t], 32, 64);
            }
        if (lane < 16) {
            atomicAdd(&gp[gmin * HID + jt0 * 16 + c], pg[0][0]);
            atomicAdd(&gp[gmin * HID + jt1 * 16 + c], pg[0][1]);
            if (gmax != gmin) {
                atomicAdd(&gp[gmax * HID + jt0 * 16 + c], pg[1][0]);
                atomicAdd(&gp[gmax * HID + jt1 * 16 + c], pg[1][1]);
            }
        }
        if (tid == 0) {
            float* gc = cntS + slice * N_GRAPHS;
            int cg = bb[0], cc = 0;
#pragma unroll
            for (int i = 0; i < NPB; ++i) {
                int g = bb[i];
                if (g != cg) { atomicAdd(&gc[cg], (float)cc); cg = g; cc = 0; }
                cc++;
            }
            atomicAdd(&gc[cg], (float)cc);
        }
    } else {
#pragma unroll
        for (int i = 0; i < 4; ++i) {
            int m = kq * 4 + i;
            size_t base = (size_t)(n0 + m) * HID;
            float v0 = d0[i] + bv0;
            float v1 = d1[i] + bv1;
            hout[base + jt0 * 16 + c] = __float2bfloat16(v0 > 0.f ? v0 : 0.f);
            hout[base + jt1 * 16 + c] = __float2bfloat16(v1 > 0.f ? v1 : 0.f);
        }
    }
}

// ---------------- Head: reduce slices + linear ----------------

__global__ __launch_bounds__(256) void final_kernel(
        const float* __restrict__ poolS, const float* __restrict__ cntS,
        const float* __restrict__ Wlin, const float* __restrict__ blin,
        float* __restrict__ out) {
    __shared__ float pl[N_GRAPHS * HID];
    __shared__ float cs[N_GRAPHS];
    int tid = threadIdx.x;
    for (int i = tid; i < N_GRAPHS * HID; i += 256) {
        float s = 0.f;
        for (int sl = 0; sl < NSLICE; ++sl) s += poolS[(size_t)sl * N_GRAPHS * HID + i];
        pl[i] = s;
    }
    if (tid < N_GRAPHS) {
        float s = 0.f;
        for (int sl = 0; sl < NSLICE; ++sl) s += cntS[sl * N_GRAPHS + tid];
        cs[tid] = s;
    }
    __syncthreads();
    if (tid < N_GRAPHS * N_CLASS) {
        int g = tid / N_CLASS, c = tid % N_CLASS;
        float invc = 1.f / fmaxf(cs[g], 1.f);
        float acc = blin[c];
        for (int j = 0; j < HID; ++j) acc += pl[g * HID + j] * invc * Wlin[j * N_CLASS + c];
        out[tid] = acc;
    }
}

extern "C" void kernel_launch(void* const* d_in, const int* in_sizes, int n_in,
                              void* d_out, int out_size, void* d_ws, size_t ws_size,
                              hipStream_t stream) {
    const float* x    = (const float*)d_in[0];
    const int*   ei   = (const int*)d_in[1];
    const float* ea   = (const float*)d_in[2];
    const int*   batch= (const int*)d_in[3];
    const float* We1  = (const float*)d_in[4];
    const float* be1  = (const float*)d_in[5];
    const float* W1   = (const float*)d_in[6];
    const float* b1   = (const float*)d_in[7];
    const float* We2  = (const float*)d_in[8];
    const float* be2  = (const float*)d_in[9];
    const float* W2   = (const float*)d_in[10];
    const float* b2   = (const float*)d_in[11];
    const float* We3  = (const float*)d_in[12];
    const float* be3  = (const float*)d_in[13];
    const float* W3   = (const float*)d_in[14];
    const float* b3   = (const float*)d_in[15];
    const float* Wlin = (const float*)d_in[16];
    const float* blin = (const float*)d_in[17];

    const int* src = ei;
    const int* dst = ei + N_EDGES;

    // workspace layout (csr first: 16B-aligned at base)
    char* w = (char*)d_ws;
    int2*  csr    = (int2*)w;                    w += sizeof(int2) * (size_t)N_EDGES;   // 12.8 MB
    bf16*  Wp2    = (bf16*)w;                    w += sizeof(bf16) * 8 * 4 * 64 * 8;    // 32 KB
    bf16*  Wp3    = (bf16*)w;                    w += sizeof(bf16) * 8 * 4 * 64 * 8;    // 32 KB
    bf16*  Wp1    = (bf16*)w;                    w += sizeof(bf16) * 8 * 64 * 8;        // 8 KB
    bf16*  xp     = (bf16*)w;                    w += sizeof(bf16) * (size_t)N_NODES * 8; // 1.6 MB
    bf16*  A      = (bf16*)w;                    w += sizeof(bf16) * (size_t)N_NODES * HID; // 25.6 MB
    bf16*  B      = (bf16*)w;                    w += sizeof(bf16) * (size_t)N_NODES * HID; // 25.6 MB
    float* poolS  = (float*)w;                   w += sizeof(float) * NSLICE * N_GRAPHS * HID; // 128 KB
    float* cntS   = (float*)w;                   w += sizeof(float) * NSLICE * N_GRAPHS;
    int*   rowptr = (int*)w;                     w += sizeof(int) * (N_NODES + 1);
    int*   gcnt   = (int*)w;                     w += sizeof(int) * NBKT;
    int*   bstart = (int*)w;                     w += sizeof(int) * NBKT;
    int*   bcur   = (int*)w;                     w += sizeof(int) * NBKT;

    // partition temporaries alias A (25.6 MB >= 12.8 + 6.4); A is first written
    // by layer1_fused, strictly after bucket_sort on the same stream.
    int2* tmp2 = (int2*)A;
    int*  tmpd = (int*)((char*)A + sizeof(int2) * (size_t)N_EDGES);

    // ---- prologue (packs + hist fused) + CSR build (9 dispatches total) ----
    hipMemsetAsync(gcnt, 0, sizeof(int) * NBKT, stream);
    prologue_kernel<<<18 + XP_BLKS + NHTILE, 256, 0, stream>>>(
        W2, W3, W1, x, dst, Wp2, Wp3, Wp1, xp, gcnt);
    scan_buckets<<<1, 256, 0, stream>>>(gcnt, bstart, bcur, rowptr, poolS);
    partition_kernel<<<NHTILE, 256, 0, stream>>>(src, dst, ea, bcur, tmp2, tmpd);
    bucket_sort<<<NBKT, 512, 0, stream>>>(tmp2, tmpd, bstart, gcnt, rowptr, csr);

    // ---- Layer 1 (fused gather + MFMA, packed x) ----
    layer1_fused<<<N_NODES / NPB, 256, 0, stream>>>(xp, csr, rowptr, We1, be1, Wp1, b1, A);

    // ---- Layer 2: A -> B ----
    hidden_layer<0><<<N_NODES / NPB, 256, 0, stream>>>(A, csr, rowptr, We2, be2, Wp2, b2, B,
                                                       batch, nullptr, nullptr);

    // ---- Layer 3: B -> sliced pool (register accum, no h3 write) ----
    hidden_layer<1><<<N_NODES / NPB, 256, 0, stream>>>(B, csr, rowptr, We3, be3, Wp3, b3, nullptr,
                                                       batch, poolS, cntS);

    // ---- Head (slice reduce + linear) ----
    final_kernel<<<1, 256, 0, stream>>>(poolS, cntS, Wlin, blin, (float*)d_out);
}